// Round 11
// baseline (175.233 us; speedup 1.0000x reference)
//
#include <hip/hip_runtime.h>
#include <math.h>

#define N_HEADC 16
#define D_MODELC 1024
#define D_HEADC 64
#define QLENC 1024
#define BSZC 2
#define MEMLENC 1024
#define KLENC 2048
#define SCALEC 0.125f
#define SL2C 0.18033688011112042f   // SCALE * log2(e)
#define LN_EPSC 1e-5f
#define RINGC 192

typedef __attribute__((ext_vector_type(8))) short short8;
typedef __attribute__((ext_vector_type(4))) float f32x4;

#define MFMA16(a, b, c) __builtin_amdgcn_mfma_f32_16x16x32_bf16((a), (b), (c), 0, 0, 0)

__device__ inline unsigned short f2bf(float x) {
    union { float f; unsigned int u; } c; c.f = x;
    unsigned int r = c.u + 0x7FFFu + ((c.u >> 16) & 1u);
    return (unsigned short)(r >> 16);
}
__device__ inline unsigned int pk2(float a, float b) { // 2xbf16 trunc pack
    union { float f; unsigned int u; } x, y; x.f = a; y.f = b;
    return (x.u >> 16) | (y.u & 0xFFFF0000u);
}
__device__ inline float bf2f(short s) {
    union { unsigned int u; float f; } c; c.u = ((unsigned int)(unsigned short)s) << 16;
    return c.f;
}

// async global->LDS, 16B per lane; lds dest = wave-uniform base + lane*16
__device__ __forceinline__ void load_lds16(const short* g, short* l) {
    __builtin_amdgcn_global_load_lds(
        (const __attribute__((address_space(1))) void*)g,
        (__attribute__((address_space(3))) void*)l,
        16, 0, 0);
}

// ---------------------------------------------------------------------------
// Fused prep: z<5 -> transpose+cast W_z; z>=5 -> flat bf16 casts (cat, r)
// grid (16,16,17)
// ---------------------------------------------------------------------------
__global__ __launch_bounds__(256) void prep_kernel(
    const float* __restrict__ mems, const float* __restrict__ wIn,
    const float* __restrict__ rIn,
    const float* __restrict__ W0, const float* __restrict__ W1,
    const float* __restrict__ W2, const float* __restrict__ W3,
    const float* __restrict__ W4,
    short* __restrict__ cat_bf, short* __restrict__ r_bf,
    short* __restrict__ D0, short* __restrict__ D1, short* __restrict__ D2,
    short* __restrict__ D3, short* __restrict__ D4)
{
    __shared__ short tile[64][72];
    const int z = blockIdx.z;
    const int t = threadIdx.x;

    if (z >= 5) {
        // casts: 3072 linear blocks x 2048 elems
        int lb = (z - 5) * 256 + blockIdx.y * 16 + blockIdx.x;
        int idx = (lb * 256 + t) * 8;
        const float* src; short* dst;
        if (idx < 4194304) {            // cat = [mems(2M); w(2M)]
            src = (idx < 2097152) ? (mems + idx) : (wIn + idx - 2097152);
            dst = cat_bf + idx;
        } else {
            src = rIn + (idx - 4194304);
            dst = r_bf + (idx - 4194304);
        }
        short8 o;
        #pragma unroll
        for (int e = 0; e < 8; ++e) o[e] = (short)f2bf(src[e]);
        *(short8*)dst = o;
        return;
    }

    const float* W; short* D;
    switch (z) {
        case 0: W = W0; D = D0; break;
        case 1: W = W1; D = D1; break;
        case 2: W = W2; D = D2; break;
        case 3: W = W3; D = D3; break;
        default: W = W4; D = D4; break;
    }
    const int n0 = blockIdx.x * 64, k0 = blockIdx.y * 64;
    #pragma unroll
    for (int it = 0; it < 2; ++it) {
        int idx = t + it * 256;
        int kl = idx >> 3, c8 = idx & 7;
        const float* src = W + (size_t)(k0 + kl) * D_MODELC + n0 + c8 * 8;
        short8 s;
        #pragma unroll
        for (int e = 0; e < 8; ++e) s[e] = (short)f2bf(src[e]);
        *(short8*)&tile[kl][c8 * 8] = s;
    }
    __syncthreads();
    #pragma unroll
    for (int it = 0; it < 2; ++it) {
        int idx = t + it * 256;
        int nl = idx >> 3, c8 = idx & 7;
        short8 s;
        #pragma unroll
        for (int e = 0; e < 8; ++e) s[e] = tile[c8 * 8 + e][nl];
        *(short8*)(D + (size_t)(n0 + nl) * D_MODELC + k0 + c8 * 8) = s;
    }
}

// ---------------------------------------------------------------------------
// V transpose: v_bf [4096][1024] (row=j*2+b, col=n*64+d) -> vt [b][n][d=64][j=2048]
// ---------------------------------------------------------------------------
__global__ __launch_bounds__(256) void vtrans_kernel(
    const short* __restrict__ v_bf, short* __restrict__ vt)
{
    __shared__ short tile[64][72];
    const int t = threadIdx.x;
    const int j0 = blockIdx.x * 64;
    const int bn = blockIdx.y;
    const int b = bn & 1, n = bn >> 1;
    #pragma unroll
    for (int it = 0; it < 2; ++it) {
        int idx = t + it * 256;
        int jl = idx >> 3, c8 = idx & 7;
        short8 s = *(const short8*)(v_bf + ((size_t)(j0 + jl) * 2 + b) * D_MODELC + n * 64 + c8 * 8);
        *(short8*)&tile[jl][c8 * 8] = s;
    }
    __syncthreads();
    #pragma unroll
    for (int it = 0; it < 2; ++it) {
        int idx = t + it * 256;
        int dl = idx >> 3, c8 = idx & 7;
        short8 s;
        #pragma unroll
        for (int e = 0; e < 8; ++e) s[e] = tile[c8 * 8 + e][dl];
        *(short8*)(vt + ((size_t)(b * 16 + n) * 64 + dl) * (size_t)KLENC + j0 + c8 * 8) = s;
    }
}

// ---------------------------------------------------------------------------
// Fused projection GEMMs (K, V, Q, RK) via global_load_lds, 128x128 tile, BK=32.
// LDS tiles XOR-swizzled (round-8 proven structure).
// ---------------------------------------------------------------------------
__global__ __launch_bounds__(256, 3) void proj_gemm_kernel(
    const short* __restrict__ cat, const short* __restrict__ rin,
    const short* __restrict__ WqT, const short* __restrict__ WkT,
    const short* __restrict__ WvT, const short* __restrict__ WrT,
    const float* __restrict__ bq, const float* __restrict__ bk,
    const float* __restrict__ bv, const float* __restrict__ br,
    const float* __restrict__ rwb, const float* __restrict__ rrb,
    short* __restrict__ qw, short* __restrict__ qr,
    short* __restrict__ kb, short* __restrict__ vb, short* __restrict__ rk)
{
    __shared__ short As[128][32];
    __shared__ short Bs[128][32];

    const int lin = blockIdx.y * 8 + blockIdx.x;        // 0..767
    const int sw  = (lin & 7) * 96 + (lin >> 3);        // XCD-contiguous
    const int bx  = sw & 7;
    const int by  = sw >> 3;

    const short* A; const short* Bt; const float* bias; int yt, mode;
    if (by < 32)      { A = cat;                         Bt = WkT; bias = bk; yt = by;      mode = 0; }
    else if (by < 64) { A = cat;                         Bt = WvT; bias = bv; yt = by - 32; mode = 1; }
    else if (by < 80) { A = cat + (size_t)2048 * 1024;   Bt = WqT; bias = bq; yt = by - 64; mode = 2; }
    else              { A = rin;                         Bt = WrT; bias = br; yt = by - 80; mode = 3; }

    const int row0 = yt * 128, col0 = bx * 128;
    const int t = threadIdx.x;
    const int lane = t & 63, wid = t >> 6;
    const int row16 = lane & 15, g8 = lane >> 4;
    const int wr = wid >> 1, wc = wid & 1;

    f32x4 acc[4][4];
    #pragma unroll
    for (int m = 0; m < 4; ++m)
        #pragma unroll
        for (int nn = 0; nn < 4; ++nn)
            acc[m][nn] = (f32x4){0.f, 0.f, 0.f, 0.f};

    short* AsB = &As[0][0] + wid * 1024;
    short* BsB = &Bs[0][0] + wid * 1024;
    const int srow4 = lane >> 2;
    const int cs4 = (lane & 3) ^ ((lane >> 3) & 3);     // swizzled source chunk
    const short* Ag = A  + (size_t)(row0 + wid * 32 + srow4) * D_MODELC + cs4 * 8;
    const short* Bg = Bt + (size_t)(col0 + wid * 32 + srow4) * D_MODELC + cs4 * 8;
    const int xc2 = (row16 >> 1) & 3;                   // read-side xor

    for (int k0 = 0; k0 < D_MODELC; k0 += 32) {
        load_lds16(Ag + k0,              AsB);
        load_lds16(Ag + k0 + 16 * 1024,  AsB + 512);
        load_lds16(Bg + k0,              BsB);
        load_lds16(Bg + k0 + 16 * 1024,  BsB + 512);
        __syncthreads();
        short8 af[4], bfr[4];
        #pragma unroll
        for (int m = 0; m < 4; ++m)
            af[m] = *(const short8*)&As[wr * 64 + m * 16 + row16][(g8 ^ xc2) * 8];
        #pragma unroll
        for (int nn = 0; nn < 4; ++nn)
            bfr[nn] = *(const short8*)&Bs[wc * 64 + nn * 16 + row16][(g8 ^ xc2) * 8];
        __builtin_amdgcn_s_setprio(1);
        #pragma unroll
        for (int m = 0; m < 4; ++m)
            #pragma unroll
            for (int nn = 0; nn < 4; ++nn)
                acc[m][nn] = MFMA16(af[m], bfr[nn], acc[m][nn]);
        __builtin_amdgcn_s_setprio(0);
        __syncthreads();
    }

    float bvv[4], w1[4], w2[4];
    #pragma unroll
    for (int nn = 0; nn < 4; ++nn) {
        int c = col0 + wc * 64 + nn * 16 + row16;
        bvv[nn] = bias[c];
        w1[nn] = rwb[c];
        w2[nn] = rrb[c];
    }
    if (mode == 2) {
        #pragma unroll
        for (int m = 0; m < 4; ++m)
            #pragma unroll
            for (int nn = 0; nn < 4; ++nn) {
                int c = col0 + wc * 64 + nn * 16 + row16;
                #pragma unroll
                for (int reg = 0; reg < 4; ++reg) {
                    int r = row0 + wr * 64 + m * 16 + g8 * 4 + reg;
                    float v = acc[m][nn][reg] + bvv[nn];
                    // fold SCALE*log2(e) into q-side operands for attn
                    qw[(size_t)r * D_MODELC + c] = (short)f2bf((v + w1[nn]) * SL2C);
                    qr[(size_t)r * D_MODELC + c] = (short)f2bf((v + w2[nn]) * SL2C);
                }
            }
    } else {
        short* C = (mode == 0) ? kb : (mode == 1) ? vb : rk;
        #pragma unroll
        for (int m = 0; m < 4; ++m)
            #pragma unroll
            for (int nn = 0; nn < 4; ++nn) {
                int c = col0 + wc * 64 + nn * 16 + row16;
                #pragma unroll
                for (int reg = 0; reg < 4; ++reg) {
                    int r = row0 + wr * 64 + m * 16 + g8 * 4 + reg;
                    C[(size_t)r * D_MODELC + c] = (short)f2bf(acc[m][nn][reg] + bvv[nn]);
                }
            }
    }
}

// ---------------------------------------------------------------------------
// Wo GEMM, split-K=2: bf16 partials (summed + bias in LN). Round-8 loop.
// ---------------------------------------------------------------------------
__global__ __launch_bounds__(256, 3) void wo_gemm_kernel(
    const short* __restrict__ A, const short* __restrict__ Bt,
    short* __restrict__ out0, short* __restrict__ out1)
{
    __shared__ short As[128][32];
    __shared__ short Bs[128][32];
    const int kz = blockIdx.z;
    short* C = kz ? out1 : out0;
    const int row0 = blockIdx.y * 128, col0 = blockIdx.x * 128;
    const int t = threadIdx.x;
    const int lane = t & 63, wid = t >> 6;
    const int row16 = lane & 15, g8 = lane >> 4;
    const int wr = wid >> 1, wc = wid & 1;

    f32x4 acc[4][4];
    #pragma unroll
    for (int m = 0; m < 4; ++m)
        #pragma unroll
        for (int nn = 0; nn < 4; ++nn)
            acc[m][nn] = (f32x4){0.f, 0.f, 0.f, 0.f};

    short* AsB = &As[0][0] + wid * 1024;
    short* BsB = &Bs[0][0] + wid * 1024;
    const int srow4 = lane >> 2;
    const int cs4 = (lane & 3) ^ ((lane >> 3) & 3);
    const short* Ag = A  + (size_t)(row0 + wid * 32 + srow4) * D_MODELC + cs4 * 8;
    const short* Bg = Bt + (size_t)(col0 + wid * 32 + srow4) * D_MODELC + cs4 * 8;
    const int xc2 = (row16 >> 1) & 3;

    const int kbase = blockIdx.z * 512;
    for (int k0 = kbase; k0 < kbase + 512; k0 += 32) {
        load_lds16(Ag + k0,             AsB);
        load_lds16(Ag + k0 + 16 * 1024, AsB + 512);
        load_lds16(Bg + k0,             BsB);
        load_lds16(Bg + k0 + 16 * 1024, BsB + 512);
        __syncthreads();
        short8 af[4], bfr[4];
        #pragma unroll
        for (int m = 0; m < 4; ++m)
            af[m] = *(const short8*)&As[wr * 64 + m * 16 + row16][(g8 ^ xc2) * 8];
        #pragma unroll
        for (int nn = 0; nn < 4; ++nn)
            bfr[nn] = *(const short8*)&Bs[wc * 64 + nn * 16 + row16][(g8 ^ xc2) * 8];
        __builtin_amdgcn_s_setprio(1);
        #pragma unroll
        for (int m = 0; m < 4; ++m)
            #pragma unroll
            for (int nn = 0; nn < 4; ++nn)
                acc[m][nn] = MFMA16(af[m], bfr[nn], acc[m][nn]);
        __builtin_amdgcn_s_setprio(0);
        __syncthreads();
    }

    #pragma unroll
    for (int m = 0; m < 4; ++m)
        #pragma unroll
        for (int nn = 0; nn < 4; ++nn) {
            int c = col0 + wc * 64 + nn * 16 + row16;
            #pragma unroll
            for (int reg = 0; reg < 4; ++reg) {
                int r = row0 + wr * 64 + m * 16 + g8 * 4 + reg;
                C[(size_t)r * D_MODELC + c] = (short)f2bf(acc[m][nn][reg]);
            }
        }
}

// ---------------------------------------------------------------------------
// LDS-staged MFMA flash attention, S^T softmax (round-8 structure) with
// V-IN-REGISTERS: 8 global_load_dwordx4 issued at step top, consumed at PV
// ~full-step later (latency hidden). K dbuf + rk ring stay in LDS.
// One barrier per step. setprio(1) around MFMA clusters.
// ---------------------------------------------------------------------------
__global__ __launch_bounds__(256, 2) void attn_mfma_kernel(
    const short* __restrict__ qw, const short* __restrict__ qr,
    const short* __restrict__ kb, const short* __restrict__ rkb,
    const short* __restrict__ vt, short* __restrict__ av)
{
    __shared__ short Kl[2][64][64];      // 16 KB (dbuf)
    __shared__ short Rl[RINGC][64];      // 24 KB (rk ring, row = jr % 192)
    __shared__ short pun[4][1376];       // 11 KB: bdT [16][84] alias P [16][64]
    __shared__ float scb[4][16];         // sc / lsum broadcast

    const int wave = threadIdx.x >> 6, lane = threadIdx.x & 63;
    const int row16 = lane & 15, g8 = lane >> 4;
    const int srow = lane >> 3, chk = lane & 7;
    const int swz = srow & 7;            // staging source-chunk xor

    // balanced + XCD-contiguous remap: CU gets ic and 15-ic (pair sum uniform)
    const int lin = blockIdx.y * 16 + blockIdx.x;   // 0..511
    const int xcd = lin & 7;
    const int u   = lin >> 3;                        // 0..63
    const int v   = u & 31;
    const int bn  = xcd * 4 + (v >> 3);
    const int tt  = v & 7;
    const int ic  = (u >> 5) ? (15 - tt) : tt;
    const int b = bn & 1, n = bn >> 1;
    const int i0 = ic * 64;
    const int i0w = i0 + wave * 16;

    // Q fragments (row = i0w+row16, k = ks*32 + g8*8 + e), pre-scaled by SL2C
    short8 qwf[2], qrf[2];
    #pragma unroll
    for (int ks = 0; ks < 2; ++ks) {
        size_t off = ((size_t)(i0w + row16) * 2 + b) * D_MODELC + n * 64 + ks * 32 + g8 * 8;
        qwf[ks] = *(const short8*)(qw + off);
        qrf[ks] = *(const short8*)(qr + off);
    }

    // V base for in-register fragment loads (row d = dt*16+row16)
    const short* vbase = vt + ((size_t)((b * 16 + n) * 64 + row16)) * KLENC;

    // ---- prologue: stage K(0), rk window(0) = [960-i0, 1088-i0) ----
    #pragma unroll
    for (int t = 0; t < 2; ++t) {
        int rr = wave * 16 + t * 8;
        int j  = rr + srow;
        int cs = chk ^ swz;
        load_lds16(kb + ((size_t)j * 2 + b) * D_MODELC + n * 64 + cs * 8, &Kl[0][rr][0]);
    }
    {
        const int p0 = 960 - i0;                  // multiple of 8 (>=0)
        #pragma unroll
        for (int t = 0; t < 4; ++t) {
            int jrb_ = p0 + wave * 32 + t * 8;
            int slotb = jrb_ % RINGC;
            int jr = jrb_ + srow;
            int jc = jr < KLENC ? jr : KLENC - 1;
            int cs = chk ^ swz;
            load_lds16(rkb + (size_t)jc * D_MODELC + n * 64 + cs * 8, &Rl[slotb][0]);
        }
    }

    f32x4 accO[4];
    #pragma unroll
    for (int dt = 0; dt < 4; ++dt) accO[dt] = (f32x4){0.f, 0.f, 0.f, 0.f};
    float m = -INFINITY, lsum = 0.f;     // per-lane: q-row = i0w + row16 (log2 domain)

    const int T = (i0 + 63 + MEMLENC + 64) >> 6;
    const int r7 = row16 & 7;

    __syncthreads();

    int cur = 0;
    for (int s = 0; s < T; ++s) {
        const int j0 = s * 64;
        const int nxt = cur ^ 1;

        // ---------- V(s) fragments -> registers (consumed at PV, latency hidden) ----------
        short8 vf[2][4];
        #pragma unroll
        for (int ks2 = 0; ks2 < 2; ++ks2)
            #pragma unroll
            for (int dt = 0; dt < 4; ++dt)
                vf[ks2][dt] = *(const short8*)(vbase + (size_t)(dt * 16) * KLENC
                                               + j0 + ks2 * 32 + g8 * 8);

        // ---------- issue async staging for step s+1 ----------
        #pragma unroll
        for (int t = 0; t < 2; ++t) {             // K(s+1)
            int rr = wave * 16 + t * 8;
            int j  = j0 + 64 + rr + srow;
            if (j > KLENC - 1) j = KLENC - 1;
            int cs = chk ^ swz;
            load_lds16(kb + ((size_t)j * 2 + b) * D_MODELC + n * 64 + cs * 8, &Kl[nxt][rr][0]);
        }
        {
            const int nb = j0 + 1088 - i0;        // new rk rows for window(s+1)
            #pragma unroll
            for (int t = 0; t < 2; ++t) {
                int jrb_ = nb + wave * 16 + t * 8;
                int slotb = jrb_ % RINGC;
                int jr = jrb_ + srow;
                int jc = jr < KLENC ? jr : KLENC - 1;
                int cs = chk ^ swz;
                load_lds16(rkb + (size_t)jc * D_MODELC + n * 64 + cs * 8, &Rl[slotb][0]);
            }
        }

        // ---------- AC^T = MFMA(K, Qw): lane holds j=g8*4+reg(+jt*16), i=row16 ----------
        __builtin_amdgcn_s_setprio(1);
        f32x4 st[4];
        #pragma unroll
        for (int jt = 0; jt < 4; ++jt) {
            st[jt] = (f32x4){0.f, 0.f, 0.f, 0.f};
            const short* kr = &Kl[cur][jt * 16 + row16][0];
            st[jt] = MFMA16(*(const short8*)(kr + ((g8 ^ r7) * 8)),       qwf[0], st[jt]);
            st[jt] = MFMA16(*(const short8*)(kr + (((4 + g8) ^ r7) * 8)), qwf[1], st[jt]);
        }

        // ---------- BD^T over jr window from ring; bdT[i][jr_loc] packed b64 ----------
        const int jrb_w = j0 - i0w + 1008;
        const int sb = jrb_w % RINGC;
        short* bdT = &pun[wave][0];               // [16][84]
        #pragma unroll
        for (int rt = 0; rt < 5; ++rt) {
            int rsl = sb + rt * 16 + row16;
            if (rsl >= RINGC) rsl -= RINGC;
            const short* rr = &Rl[rsl][0];
            f32x4 bd = (f32x4){0.f, 0.f, 0.f, 0.f};
            bd = MFMA16(*(const short8*)(rr + ((g8 ^ r7) * 8)),       qrf[0], bd);
            bd = MFMA16(*(const short8*)(rr + (((4 + g8) ^ r7) * 8)), qrf[1], bd);
            uint2 wv;
            wv.x = pk2(bd[0], bd[1]);
            wv.y = pk2(bd[2], bd[3]);
            *(uint2*)&bdT[row16 * 84 + rt * 16 + g8 * 4] = wv;
        }
        __builtin_amdgcn_s_setprio(0);

        // ---------- combine (+mask only on tail steps; scale pre-folded) ----------
        float sl[4][4];
        if (j0 + 63 <= i0w + MEMLENC) {
            #pragma unroll
            for (int jt = 0; jt < 4; ++jt)
                #pragma unroll
                for (int reg = 0; reg < 4; ++reg) {
                    const int jl = jt * 16 + g8 * 4 + reg;
                    sl[jt][reg] = st[jt][reg] + bf2f(bdT[row16 * 84 + jl + 15 - row16]);
                }
        } else {
            #pragma unroll
            for (int jt = 0; jt < 4; ++jt)
                #pragma unroll
                for (int reg = 0; reg < 4; ++reg) {
                    const int jl = jt * 16 + g8 * 4 + reg;
                    float vv = st[jt][reg] + bf2f(bdT[row16 * 84 + jl + 15 - row16]);
                    sl[jt][reg] = (j0 + jl > i0w + row16 + MEMLENC) ? -INFINITY : vv;
                }
        }

        // ---------- in-lane max tree + 2 cross-lane steps ----------
        float mx0 = fmaxf(fmaxf(sl[0][0], sl[0][1]), fmaxf(sl[0][2], sl[0][3]));
        float mx1 = fmaxf(fmaxf(sl[1][0], sl[1][1]), fmaxf(sl[1][2], sl[1][3]));
        float mx2 = fmaxf(fmaxf(sl[2][0], sl[2][1]), fmaxf(sl[2][2], sl[2][3]));
        float mx3 = fmaxf(fmaxf(sl[3][0], sl[3][1]), fmaxf(sl[3][2], sl[3][3]));
        float mx = fmaxf(fmaxf(mx0, mx1), fmaxf(mx2, mx3));
        mx = fmaxf(mx, __shfl_xor(mx, 16, 64));
        mx = fmaxf(mx, __shfl_xor(mx, 32, 64));

        // ---------- defer-max rescale (rare) ----------
        if (__any(mx > m + 8.f)) {
            float mn = fmaxf(m, mx);
            float sc = exp2f(m - mn);            // first step: exp2(-inf)=0
            m = mn;
            lsum *= sc;
            if (lane < 16) scb[wave][lane] = sc;
            float4 s4 = *(const float4*)&scb[wave][g8 * 4];
            #pragma unroll
            for (int dt = 0; dt < 4; ++dt) {
                accO[dt][0] *= s4.x; accO[dt][1] *= s4.y;
                accO[dt][2] *= s4.z; accO[dt][3] *= s4.w;
            }
        }

        // ---------- P = exp2(S - m), packed b64 store, in-lane tree sum ----------
        #pragma unroll
        for (int jt = 0; jt < 4; ++jt)
            #pragma unroll
            for (int reg = 0; reg < 4; ++reg)
                sl[jt][reg] = exp2f(sl[jt][reg] - m);
        float ps = ((sl[0][0] + sl[0][1]) + (sl[0][2] + sl[0][3]))
                 + ((sl[1][0] + sl[1][1]) + (sl[1][2] + sl[1][3]))
                 + ((sl[2][0] + sl[2][1]) + (sl[2][2] + sl[2][3]))
                 + ((sl[3][0] + sl[3][1]) + (sl[3][2] + sl[3][3]));
        short* pP = &pun[wave][0];               // overwrites bdT (reads done, same wave)
        #pragma unroll
        for (int jt = 0; jt < 4; ++jt) {
            const int ch = (jt * 2 + (g8 >> 1)) ^ r7;
            uint2 pkd;
            pkd.x = pk2(sl[jt][0], sl[jt][1]);
            pkd.y = pk2(sl[jt][2], sl[jt][3]);
            *(uint2*)&pP[row16 * 64 + ch * 8 + (g8 & 1) * 4] = pkd;
        }
        ps += __shfl_xor(ps, 16, 64);
        ps += __shfl_xor(ps, 32, 64);
        lsum += ps;

        // ---------- PV: O += P(s) @ V(s) from registers ----------
        __builtin_amdgcn_s_setprio(1);
        #pragma unroll
        for (int ks2 = 0; ks2 < 2; ++ks2) {
            short8 pf = *(const short8*)&pP[row16 * 64 + (((ks2 * 4 + g8) ^ r7) * 8)];
            #pragma unroll
            for (int dt = 0; dt < 4; ++dt)
                accO[dt] = MFMA16(pf, vf[ks2][dt], accO[dt]);
        }
        __builtin_amdgcn_s_setprio(0);

        __syncthreads();   // drains staging: Kl[nxt]/Rl-new valid for s+1
        cur = nxt;
    }

    // ---- epilogue: broadcast lsum to accO orientation, store ----
    if (lane < 16) scb[wave][lane] = lsum;
    float4 l4 = *(const float4*)&scb[wave][g8 * 4];
    float rl4[4] = {1.f / l4.x, 1.f / l4.y, 1.f / l4.z, 1.f / l4.w};
    #pragma unroll
    for (int dt = 0; dt < 4; ++dt)
        #pragma unroll
        for (int reg = 0; reg < 4; ++reg) {
            size_t o = ((size_t)(i0w + g8 * 4 + reg) * 2 + b) * D_MODELC + n * 64 + dt * 16 + row16;
            av[o] = (short)f2bf(accO[dt][reg] * rl4[reg]);
        }
}

// ---------------------------------------------------------------------------
// Residual + bias + LayerNorm: x = w + bf(p0) + bf(p1) + bo
// ---------------------------------------------------------------------------
__global__ __launch_bounds__(256) void ln_kernel(
    const float* __restrict__ w, const short* __restrict__ p0,
    const short* __restrict__ p1, const float* __restrict__ bo,
    const float* __restrict__ g, const float* __restrict__ bb,
    float* __restrict__ out)
{
    __shared__ float red[2][4];
    const int row = blockIdx.x;
    const int lane = threadIdx.x & 63;
    const int wv = threadIdx.x >> 6;
    const size_t base = (size_t)row * D_MODELC;
    const int c = threadIdx.x * 4;

    float4 xw = *(const float4*)&w[base + c];
    ushort4 a0 = *(const ushort4*)&p0[base + c];
    ushort4 a1 = *(const ushort4*)&p1[base + c];
    float4 xb = *(const float4*)&bo[c];
    float x[4] = {xw.x + bf2f((short)a0.x) + bf2f((short)a1.x) + xb.x,
                  xw.y + bf2f((short)a0.y) + bf2f((short)a1.y) + xb.y,
                  xw.z + bf2f((short)a0.z) + bf2f((short)a1.z) + xb.z,
                  xw.w + bf2f((short)a0.w) + bf2f((short)a1.w) + xb.w};

    float sum = x[0] + x[1] + x[2] + x[3];
    float ssq = x[0]*x[0] + x[1]*x[1] + x[2]*x[2] + x[3]*x[3];
    #pragma unroll
    for (int off = 32; off > 0; off >>= 1) {
        sum += __shfl_xor(sum, off, 64);
        ssq += __shfl_xor(ssq, off, 64);
    }
    if (lane == 0) { red[0][wv] = sum; red[1][wv] = ssq; }
    __syncthreads();
    sum = red[0][0] + red[0][1] + red[0][2] + red[0][3];
    ssq = red[1][0] + red[1][1] + red[1][2] + red[1][3];

    const float mu = sum * (1.0f / D_MODELC);
    const float var = ssq * (1.0f / D_MODELC) - mu * mu;
    const float rstd = rsqrtf(var + LN_EPSC);

    float4 o;
    o.x = (x[0] - mu) * rstd * g[c] + bb[c];
    o.y = (x[1] - mu) * rstd * g[c+1] + bb[c+1];
    o.z = (x[2] - mu) * rstd * g[c+2] + bb[c+2];
    o.w = (x[3] - mu) * rstd * g[c+3] + bb[c+3];
    *(float4*)&out[base + c] = o;
}

// ---------------------------------------------------------------------------
extern "C" void kernel_launch(void* const* d_in, const int* in_sizes, int n_in,
                              void* d_out, int out_size, void* d_ws, size_t ws_size,
                              hipStream_t stream)
{
    const float* w    = (const float*)d_in[0];
    const float* r    = (const float*)d_in[1];
    const float* mems = (const float*)d_in[2];
    const float* rwb  = (const float*)d_in[3];
    const float* rrb  = (const float*)d_in[4];
    // d_in[5] = attn_mask — deterministic causal+mem pattern, handled analytically
    const float* Wq = (const float*)d_in[6];
    const float* bq = (const float*)d_in[7];
    const float* Wk = (const float*)d_in[8];
    const float* bk = (const float*)d_in[9];
    const float* Wv = (const float*)d_in[10];
    const float* bv = (const float*)d_in[11];
    const float* Wr = (const float*)d_in[12];
    const float* br = (const float*)d_in[13];
    const float* Wo = (const float*)d_in[14];
    const float* bo = (const float*)d_in[15];
    const float* ln_g = (const float*)d_in[16];
    const float* ln_b = (const float*)d_in[17];
    float* out = (float*)d_out;

    char* ws = (char*)d_ws;
    const size_t MB = 1ull << 20;
    short* cat_bf = (short*)(ws + 0 * MB);    // 8 MB
    short* r_bf   = (short*)(ws + 8 * MB);    // 4 MB
    short* Wq_t   = (short*)(ws + 12 * MB);   // dead after proj -> wo out0
    short* Wk_t   = (short*)(ws + 14 * MB);
    short* Wv_t   = (short*)(ws + 16 * MB);   // dead after proj -> wo out1
    short* Wr_t   = (short*)(ws + 18 * MB);
    short* Wo_t   = (short*)(ws + 20 * MB);   // needed until wo_gemm
    short* qw_bf  = (short*)(ws + 22 * MB);
    short* qr_bf  = (short*)(ws + 26 * MB);
    short* k_bf   = (short*)(ws + 30 * MB);   // 8 MB
    short* v_bf   = (short*)(ws + 38 * MB);   // 8 MB
    short* rk_bf  = (short*)(ws + 46 * MB);
    short* vt     = (short*)(ws + 50 * MB);   // 8 MB
    short* av_bf  = (short*)(ws + 58 * MB);
    short* wo0    = Wq_t;                     // 4 MB (12..16)
    short* wo1    = Wv_t;                     // 4 MB (16..20)

    dim3 blk(256);

    // fused casts + weight transposes
    prep_kernel<<<dim3(16, 16, 17), blk, 0, stream>>>(
        mems, w, r, Wq, Wk, Wv, Wr, Wo,
        cat_bf, r_bf, Wq_t, Wk_t, Wv_t, Wr_t, Wo_t);

    // fused projections (K, V, Q->qw/qr scaled, RK)
    proj_gemm_kernel<<<dim3(8, 96), blk, 0, stream>>>(
        cat_bf, r_bf, Wq_t, Wk_t, Wv_t, Wr_t,
        bq, bk, bv, br, rwb, rrb,
        qw_bf, qr_bf, k_bf, v_bf, rk_bf);

    // V transpose
    vtrans_kernel<<<dim3(32, 32), blk, 0, stream>>>(v_bf, vt);

    // attention (LDS-staged K/rk, V-in-regs): grid 512
    attn_mfma_kernel<<<dim3(16, 32), blk, 0, stream>>>(
        qw_bf, qr_bf, k_bf, rk_bf, vt, av_bf);

    // output projection split-K (bf16 partials; summed + bias in LN)
    wo_gemm_kernel<<<dim3(8, 16, 2), blk, 0, stream>>>(av_bf, Wo_t, wo0, wo1);

    // LN(w + wo0 + wo1 + bo)
    ln_kernel<<<dim3(2048), blk, 0, stream>>>(w, wo0, wo1, bo, ln_g, ln_b, out);
}

// Round 12
// 152.171 us; speedup vs baseline: 1.1516x; 1.1516x over previous
//
#include <hip/hip_runtime.h>
#include <math.h>

#define N_HEADC 16
#define D_MODELC 1024
#define D_HEADC 64
#define QLENC 1024
#define BSZC 2
#define MEMLENC 1024
#define KLENC 2048
#define SCALEC 0.125f
#define SL2C 0.18033688011112042f   // SCALE * log2(e)
#define LN_EPSC 1e-5f
#define RINGC 192

typedef __attribute__((ext_vector_type(8))) short short8;
typedef __attribute__((ext_vector_type(4))) float f32x4;

#define MFMA16(a, b, c) __builtin_amdgcn_mfma_f32_16x16x32_bf16((a), (b), (c), 0, 0, 0)

__device__ inline unsigned short f2bf(float x) {
    union { float f; unsigned int u; } c; c.f = x;
    unsigned int r = c.u + 0x7FFFu + ((c.u >> 16) & 1u);
    return (unsigned short)(r >> 16);
}
__device__ inline unsigned int pk2(float a, float b) { // 2xbf16 trunc pack
    union { float f; unsigned int u; } x, y; x.f = a; y.f = b;
    return (x.u >> 16) | (y.u & 0xFFFF0000u);
}
__device__ inline float bf2f(short s) {
    union { unsigned int u; float f; } c; c.u = ((unsigned int)(unsigned short)s) << 16;
    return c.f;
}

// async global->LDS, 16B per lane; lds dest = wave-uniform base + lane*16
__device__ __forceinline__ void load_lds16(const short* g, short* l) {
    __builtin_amdgcn_global_load_lds(
        (const __attribute__((address_space(1))) void*)g,
        (__attribute__((address_space(3))) void*)l,
        16, 0, 0);
}

// ---------------------------------------------------------------------------
// Fused prep: z<5 -> transpose+cast W_z; z>=5 -> flat bf16 casts (cat, r)
// grid (16,16,17)
// ---------------------------------------------------------------------------
__global__ __launch_bounds__(256) void prep_kernel(
    const float* __restrict__ mems, const float* __restrict__ wIn,
    const float* __restrict__ rIn,
    const float* __restrict__ W0, const float* __restrict__ W1,
    const float* __restrict__ W2, const float* __restrict__ W3,
    const float* __restrict__ W4,
    short* __restrict__ cat_bf, short* __restrict__ r_bf,
    short* __restrict__ D0, short* __restrict__ D1, short* __restrict__ D2,
    short* __restrict__ D3, short* __restrict__ D4)
{
    __shared__ short tile[64][72];
    const int z = blockIdx.z;
    const int t = threadIdx.x;

    if (z >= 5) {
        int lb = (z - 5) * 256 + blockIdx.y * 16 + blockIdx.x;
        int idx = (lb * 256 + t) * 8;
        const float* src; short* dst;
        if (idx < 4194304) {            // cat = [mems(2M); w(2M)]
            src = (idx < 2097152) ? (mems + idx) : (wIn + idx - 2097152);
            dst = cat_bf + idx;
        } else {
            src = rIn + (idx - 4194304);
            dst = r_bf + (idx - 4194304);
        }
        short8 o;
        #pragma unroll
        for (int e = 0; e < 8; ++e) o[e] = (short)f2bf(src[e]);
        *(short8*)dst = o;
        return;
    }

    const float* W; short* D;
    switch (z) {
        case 0: W = W0; D = D0; break;
        case 1: W = W1; D = D1; break;
        case 2: W = W2; D = D2; break;
        case 3: W = W3; D = D3; break;
        default: W = W4; D = D4; break;
    }
    const int n0 = blockIdx.x * 64, k0 = blockIdx.y * 64;
    #pragma unroll
    for (int it = 0; it < 2; ++it) {
        int idx = t + it * 256;
        int kl = idx >> 3, c8 = idx & 7;
        const float* src = W + (size_t)(k0 + kl) * D_MODELC + n0 + c8 * 8;
        short8 s;
        #pragma unroll
        for (int e = 0; e < 8; ++e) s[e] = (short)f2bf(src[e]);
        *(short8*)&tile[kl][c8 * 8] = s;
    }
    __syncthreads();
    #pragma unroll
    for (int it = 0; it < 2; ++it) {
        int idx = t + it * 256;
        int nl = idx >> 3, c8 = idx & 7;
        short8 s;
        #pragma unroll
        for (int e = 0; e < 8; ++e) s[e] = tile[c8 * 8 + e][nl];
        *(short8*)(D + (size_t)(n0 + nl) * D_MODELC + k0 + c8 * 8) = s;
    }
}

// ---------------------------------------------------------------------------
// V transpose: v_bf [4096][1024] (row=j*2+b, col=n*64+d) -> vt [b][n][d=64][j=2048]
// ---------------------------------------------------------------------------
__global__ __launch_bounds__(256) void vtrans_kernel(
    const short* __restrict__ v_bf, short* __restrict__ vt)
{
    __shared__ short tile[64][72];
    const int t = threadIdx.x;
    const int j0 = blockIdx.x * 64;
    const int bn = blockIdx.y;
    const int b = bn & 1, n = bn >> 1;
    #pragma unroll
    for (int it = 0; it < 2; ++it) {
        int idx = t + it * 256;
        int jl = idx >> 3, c8 = idx & 7;
        short8 s = *(const short8*)(v_bf + ((size_t)(j0 + jl) * 2 + b) * D_MODELC + n * 64 + c8 * 8);
        *(short8*)&tile[jl][c8 * 8] = s;
    }
    __syncthreads();
    #pragma unroll
    for (int it = 0; it < 2; ++it) {
        int idx = t + it * 256;
        int dl = idx >> 3, c8 = idx & 7;
        short8 s;
        #pragma unroll
        for (int e = 0; e < 8; ++e) s[e] = tile[c8 * 8 + e][dl];
        *(short8*)(vt + ((size_t)(b * 16 + n) * 64 + dl) * (size_t)KLENC + j0 + c8 * 8) = s;
    }
}

// ---------------------------------------------------------------------------
// Fused projection GEMMs (K, V, Q, RK) via global_load_lds, 128x128 tile, BK=32.
// LDS tiles XOR-swizzled (round-8 proven structure, verbatim loop).
// ---------------------------------------------------------------------------
__global__ __launch_bounds__(256, 3) void proj_gemm_kernel(
    const short* __restrict__ cat, const short* __restrict__ rin,
    const short* __restrict__ WqT, const short* __restrict__ WkT,
    const short* __restrict__ WvT, const short* __restrict__ WrT,
    const float* __restrict__ bq, const float* __restrict__ bk,
    const float* __restrict__ bv, const float* __restrict__ br,
    const float* __restrict__ rwb, const float* __restrict__ rrb,
    short* __restrict__ qw, short* __restrict__ qr,
    short* __restrict__ kb, short* __restrict__ vb, short* __restrict__ rk)
{
    __shared__ short As[128][32];
    __shared__ short Bs[128][32];

    const int lin = blockIdx.y * 8 + blockIdx.x;        // 0..767
    const int sw  = (lin & 7) * 96 + (lin >> 3);        // XCD-contiguous
    const int bx  = sw & 7;
    const int by  = sw >> 3;

    const short* A; const short* Bt; const float* bias; int yt, mode;
    if (by < 32)      { A = cat;                         Bt = WkT; bias = bk; yt = by;      mode = 0; }
    else if (by < 64) { A = cat;                         Bt = WvT; bias = bv; yt = by - 32; mode = 1; }
    else if (by < 80) { A = cat + (size_t)2048 * 1024;   Bt = WqT; bias = bq; yt = by - 64; mode = 2; }
    else              { A = rin;                         Bt = WrT; bias = br; yt = by - 80; mode = 3; }

    const int row0 = yt * 128, col0 = bx * 128;
    const int t = threadIdx.x;
    const int lane = t & 63, wid = t >> 6;
    const int row16 = lane & 15, g8 = lane >> 4;
    const int wr = wid >> 1, wc = wid & 1;

    f32x4 acc[4][4];
    #pragma unroll
    for (int m = 0; m < 4; ++m)
        #pragma unroll
        for (int nn = 0; nn < 4; ++nn)
            acc[m][nn] = (f32x4){0.f, 0.f, 0.f, 0.f};

    short* AsB = &As[0][0] + wid * 1024;
    short* BsB = &Bs[0][0] + wid * 1024;
    const int srow4 = lane >> 2;
    const int cs4 = (lane & 3) ^ ((lane >> 3) & 3);     // swizzled source chunk
    const short* Ag = A  + (size_t)(row0 + wid * 32 + srow4) * D_MODELC + cs4 * 8;
    const short* Bg = Bt + (size_t)(col0 + wid * 32 + srow4) * D_MODELC + cs4 * 8;
    const int xc2 = (row16 >> 1) & 3;                   // read-side xor

    for (int k0 = 0; k0 < D_MODELC; k0 += 32) {
        load_lds16(Ag + k0,              AsB);
        load_lds16(Ag + k0 + 16 * 1024,  AsB + 512);
        load_lds16(Bg + k0,              BsB);
        load_lds16(Bg + k0 + 16 * 1024,  BsB + 512);
        __syncthreads();
        short8 af[4], bfr[4];
        #pragma unroll
        for (int m = 0; m < 4; ++m)
            af[m] = *(const short8*)&As[wr * 64 + m * 16 + row16][(g8 ^ xc2) * 8];
        #pragma unroll
        for (int nn = 0; nn < 4; ++nn)
            bfr[nn] = *(const short8*)&Bs[wc * 64 + nn * 16 + row16][(g8 ^ xc2) * 8];
        #pragma unroll
        for (int m = 0; m < 4; ++m)
            #pragma unroll
            for (int nn = 0; nn < 4; ++nn)
                acc[m][nn] = MFMA16(af[m], bfr[nn], acc[m][nn]);
        __syncthreads();
    }

    float bvv[4], w1[4], w2[4];
    #pragma unroll
    for (int nn = 0; nn < 4; ++nn) {
        int c = col0 + wc * 64 + nn * 16 + row16;
        bvv[nn] = bias[c];
        w1[nn] = rwb[c];
        w2[nn] = rrb[c];
    }
    if (mode == 2) {
        #pragma unroll
        for (int m = 0; m < 4; ++m)
            #pragma unroll
            for (int nn = 0; nn < 4; ++nn) {
                int c = col0 + wc * 64 + nn * 16 + row16;
                #pragma unroll
                for (int reg = 0; reg < 4; ++reg) {
                    int r = row0 + wr * 64 + m * 16 + g8 * 4 + reg;
                    float v = acc[m][nn][reg] + bvv[nn];
                    // fold SCALE*log2(e) into q-side operands for attn
                    qw[(size_t)r * D_MODELC + c] = (short)f2bf((v + w1[nn]) * SL2C);
                    qr[(size_t)r * D_MODELC + c] = (short)f2bf((v + w2[nn]) * SL2C);
                }
            }
    } else {
        short* C = (mode == 0) ? kb : (mode == 1) ? vb : rk;
        #pragma unroll
        for (int m = 0; m < 4; ++m)
            #pragma unroll
            for (int nn = 0; nn < 4; ++nn) {
                int c = col0 + wc * 64 + nn * 16 + row16;
                #pragma unroll
                for (int reg = 0; reg < 4; ++reg) {
                    int r = row0 + wr * 64 + m * 16 + g8 * 4 + reg;
                    C[(size_t)r * D_MODELC + c] = (short)f2bf(acc[m][nn][reg] + bvv[nn]);
                }
            }
    }
}

// ---------------------------------------------------------------------------
// Wo GEMM, split-K=2: bf16 partials (summed + bias in LN). Round-8 loop.
// ---------------------------------------------------------------------------
__global__ __launch_bounds__(256, 3) void wo_gemm_kernel(
    const short* __restrict__ A, const short* __restrict__ Bt,
    short* __restrict__ out0, short* __restrict__ out1)
{
    __shared__ short As[128][32];
    __shared__ short Bs[128][32];
    const int kz = blockIdx.z;
    short* C = kz ? out1 : out0;
    const int row0 = blockIdx.y * 128, col0 = blockIdx.x * 128;
    const int t = threadIdx.x;
    const int lane = t & 63, wid = t >> 6;
    const int row16 = lane & 15, g8 = lane >> 4;
    const int wr = wid >> 1, wc = wid & 1;

    f32x4 acc[4][4];
    #pragma unroll
    for (int m = 0; m < 4; ++m)
        #pragma unroll
        for (int nn = 0; nn < 4; ++nn)
            acc[m][nn] = (f32x4){0.f, 0.f, 0.f, 0.f};

    short* AsB = &As[0][0] + wid * 1024;
    short* BsB = &Bs[0][0] + wid * 1024;
    const int srow4 = lane >> 2;
    const int cs4 = (lane & 3) ^ ((lane >> 3) & 3);
    const short* Ag = A  + (size_t)(row0 + wid * 32 + srow4) * D_MODELC + cs4 * 8;
    const short* Bg = Bt + (size_t)(col0 + wid * 32 + srow4) * D_MODELC + cs4 * 8;
    const int xc2 = (row16 >> 1) & 3;

    const int kbase = kz * 512;
    for (int k0 = kbase; k0 < kbase + 512; k0 += 32) {
        load_lds16(Ag + k0,             AsB);
        load_lds16(Ag + k0 + 16 * 1024, AsB + 512);
        load_lds16(Bg + k0,             BsB);
        load_lds16(Bg + k0 + 16 * 1024, BsB + 512);
        __syncthreads();
        short8 af[4], bfr[4];
        #pragma unroll
        for (int m = 0; m < 4; ++m)
            af[m] = *(const short8*)&As[wr * 64 + m * 16 + row16][(g8 ^ xc2) * 8];
        #pragma unroll
        for (int nn = 0; nn < 4; ++nn)
            bfr[nn] = *(const short8*)&Bs[wc * 64 + nn * 16 + row16][(g8 ^ xc2) * 8];
        #pragma unroll
        for (int m = 0; m < 4; ++m)
            #pragma unroll
            for (int nn = 0; nn < 4; ++nn)
                acc[m][nn] = MFMA16(af[m], bfr[nn], acc[m][nn]);
        __syncthreads();
    }

    #pragma unroll
    for (int m = 0; m < 4; ++m)
        #pragma unroll
        for (int nn = 0; nn < 4; ++nn) {
            int c = col0 + wc * 64 + nn * 16 + row16;
            #pragma unroll
            for (int reg = 0; reg < 4; ++reg) {
                int r = row0 + wr * 64 + m * 16 + g8 * 4 + reg;
                C[(size_t)r * D_MODELC + c] = (short)f2bf(acc[m][nn][reg]);
            }
        }
}

// ---------------------------------------------------------------------------
// LDS-staged MFMA flash attention, S^T softmax (round-8 structure, verbatim).
// Block = 64 q-rows (4 waves i-split) x one (b,n); K dbuf, V dbuf, rk ring.
// ONE barrier per step. q pre-scaled by SCALE*log2e; mask only on tail steps.
// ---------------------------------------------------------------------------
__global__ __launch_bounds__(256, 2) void attn_mfma_kernel(
    const short* __restrict__ qw, const short* __restrict__ qr,
    const short* __restrict__ kb, const short* __restrict__ rkb,
    const short* __restrict__ vt, short* __restrict__ av)
{
    __shared__ short Kl[2][64][64];      // 16 KB (dbuf)
    __shared__ short Vl[2][64][64];      // 16 KB (dbuf, [d][j])
    __shared__ short Rl[RINGC][64];      // 24 KB (rk ring, row = jr % 192)
    __shared__ short pun[4][1376];       // 11 KB: bdT [16][84] alias P [16][64]
    __shared__ float scb[4][16];         // sc / lsum broadcast

    const int wave = threadIdx.x >> 6, lane = threadIdx.x & 63;
    const int row16 = lane & 15, g8 = lane >> 4;
    const int srow = lane >> 3, chk = lane & 7;
    const int swz = srow & 7;            // staging source-chunk xor

    // balanced + XCD-contiguous remap: CU gets ic and 15-ic (pair sum uniform)
    const int lin = blockIdx.y * 16 + blockIdx.x;   // 0..511
    const int xcd = lin & 7;
    const int u   = lin >> 3;                        // 0..63
    const int v   = u & 31;
    const int bn  = xcd * 4 + (v >> 3);
    const int tt  = v & 7;
    const int ic  = (u >> 5) ? (15 - tt) : tt;
    const int b = bn & 1, n = bn >> 1;
    const int i0 = ic * 64;
    const int i0w = i0 + wave * 16;

    // Q fragments (row = i0w+row16, k = ks*32 + g8*8 + e), pre-scaled by SL2C
    short8 qwf[2], qrf[2];
    #pragma unroll
    for (int ks = 0; ks < 2; ++ks) {
        size_t off = ((size_t)(i0w + row16) * 2 + b) * D_MODELC + n * 64 + ks * 32 + g8 * 8;
        qwf[ks] = *(const short8*)(qw + off);
        qrf[ks] = *(const short8*)(qr + off);
    }

    // ---- prologue: stage K(0), V(0), rk window(0) = [960-i0, 1088-i0) ----
    #pragma unroll
    for (int t = 0; t < 2; ++t) {
        int rr = wave * 16 + t * 8;
        int j  = rr + srow;
        int cs = chk ^ swz;
        load_lds16(kb + ((size_t)j * 2 + b) * D_MODELC + n * 64 + cs * 8, &Kl[0][rr][0]);
        load_lds16(vt + ((size_t)((b * 16 + n) * 64 + rr + srow)) * KLENC + cs * 8,
                   &Vl[0][rr][0]);
    }
    {
        const int p0 = 960 - i0;                  // multiple of 8 (>=0)
        #pragma unroll
        for (int t = 0; t < 4; ++t) {
            int jrb_ = p0 + wave * 32 + t * 8;
            int slotb = jrb_ % RINGC;
            int jr = jrb_ + srow;
            int jc = jr < KLENC ? jr : KLENC - 1;
            int cs = chk ^ swz;
            load_lds16(rkb + (size_t)jc * D_MODELC + n * 64 + cs * 8, &Rl[slotb][0]);
        }
    }

    f32x4 accO[4];
    #pragma unroll
    for (int dt = 0; dt < 4; ++dt) accO[dt] = (f32x4){0.f, 0.f, 0.f, 0.f};
    float m = -INFINITY, lsum = 0.f;     // per-lane: q-row = i0w + row16 (log2 domain)

    const int T = (i0 + 63 + MEMLENC + 64) >> 6;
    const int r7 = row16 & 7;

    __syncthreads();

    int cur = 0;
    for (int s = 0; s < T; ++s) {
        const int j0 = s * 64;
        const int nxt = cur ^ 1;

        // ---------- issue async staging for step s+1 ----------
        #pragma unroll
        for (int t = 0; t < 2; ++t) {             // K(s+1)
            int rr = wave * 16 + t * 8;
            int j  = j0 + 64 + rr + srow;
            if (j > KLENC - 1) j = KLENC - 1;
            int cs = chk ^ swz;
            load_lds16(kb + ((size_t)j * 2 + b) * D_MODELC + n * 64 + cs * 8, &Kl[nxt][rr][0]);
        }
        {
            const int nb = j0 + 1088 - i0;        // new rk rows for window(s+1)
            #pragma unroll
            for (int t = 0; t < 2; ++t) {
                int jrb_ = nb + wave * 16 + t * 8;
                int slotb = jrb_ % RINGC;
                int jr = jrb_ + srow;
                int jc = jr < KLENC ? jr : KLENC - 1;
                int cs = chk ^ swz;
                load_lds16(rkb + (size_t)jc * D_MODELC + n * 64 + cs * 8, &Rl[slotb][0]);
            }
        }
        {
            const int jsrc = (j0 + 64 <= KLENC - 64) ? (j0 + 64) : (KLENC - 64);
            #pragma unroll
            for (int t = 0; t < 2; ++t) {         // V(s+1), d-major
                int rr = wave * 16 + t * 8;
                int cs = chk ^ swz;
                load_lds16(vt + ((size_t)((b * 16 + n) * 64 + rr + srow)) * KLENC + jsrc + cs * 8,
                           &Vl[nxt][rr][0]);
            }
        }

        // ---------- AC^T = MFMA(K, Qw): lane holds j=g8*4+reg(+jt*16), i=row16 ----------
        __builtin_amdgcn_s_setprio(1);
        f32x4 st[4];
        #pragma unroll
        for (int jt = 0; jt < 4; ++jt) {
            st[jt] = (f32x4){0.f, 0.f, 0.f, 0.f};
            const short* kr = &Kl[cur][jt * 16 + row16][0];
            st[jt] = MFMA16(*(const short8*)(kr + ((g8 ^ r7) * 8)),       qwf[0], st[jt]);
            st[jt] = MFMA16(*(const short8*)(kr + (((4 + g8) ^ r7) * 8)), qwf[1], st[jt]);
        }

        // ---------- BD^T over jr window from ring; bdT[i][jr_loc] packed b64 ----------
        const int jrb_w = j0 - i0w + 1008;
        const int sb = jrb_w % RINGC;
        short* bdT = &pun[wave][0];               // [16][84]
        #pragma unroll
        for (int rt = 0; rt < 5; ++rt) {
            int rsl = sb + rt * 16 + row16;
            if (rsl >= RINGC) rsl -= RINGC;
            const short* rr = &Rl[rsl][0];
            f32x4 bd = (f32x4){0.f, 0.f, 0.f, 0.f};
            bd = MFMA16(*(const short8*)(rr + ((g8 ^ r7) * 8)),       qrf[0], bd);
            bd = MFMA16(*(const short8*)(rr + (((4 + g8) ^ r7) * 8)), qrf[1], bd);
            uint2 wv;
            wv.x = pk2(bd[0], bd[1]);
            wv.y = pk2(bd[2], bd[3]);
            *(uint2*)&bdT[row16 * 84 + rt * 16 + g8 * 4] = wv;
        }
        __builtin_amdgcn_s_setprio(0);

        // ---------- combine (+mask only on tail steps; scale pre-folded) ----------
        float sl[4][4];
        if (j0 + 63 <= i0w + MEMLENC) {
            #pragma unroll
            for (int jt = 0; jt < 4; ++jt)
                #pragma unroll
                for (int reg = 0; reg < 4; ++reg) {
                    const int jl = jt * 16 + g8 * 4 + reg;
                    sl[jt][reg] = st[jt][reg] + bf2f(bdT[row16 * 84 + jl + 15 - row16]);
                }
        } else {
            #pragma unroll
            for (int jt = 0; jt < 4; ++jt)
                #pragma unroll
                for (int reg = 0; reg < 4; ++reg) {
                    const int jl = jt * 16 + g8 * 4 + reg;
                    float vv = st[jt][reg] + bf2f(bdT[row16 * 84 + jl + 15 - row16]);
                    sl[jt][reg] = (j0 + jl > i0w + row16 + MEMLENC) ? -INFINITY : vv;
                }
        }

        // ---------- in-lane max tree + 2 cross-lane steps ----------
        float mx0 = fmaxf(fmaxf(sl[0][0], sl[0][1]), fmaxf(sl[0][2], sl[0][3]));
        float mx1 = fmaxf(fmaxf(sl[1][0], sl[1][1]), fmaxf(sl[1][2], sl[1][3]));
        float mx2 = fmaxf(fmaxf(sl[2][0], sl[2][1]), fmaxf(sl[2][2], sl[2][3]));
        float mx3 = fmaxf(fmaxf(sl[3][0], sl[3][1]), fmaxf(sl[3][2], sl[3][3]));
        float mx = fmaxf(fmaxf(mx0, mx1), fmaxf(mx2, mx3));
        mx = fmaxf(mx, __shfl_xor(mx, 16, 64));
        mx = fmaxf(mx, __shfl_xor(mx, 32, 64));

        // ---------- defer-max rescale (rare) ----------
        if (__any(mx > m + 8.f)) {
            float mn = fmaxf(m, mx);
            float sc = exp2f(m - mn);            // first step: exp2(-inf)=0
            m = mn;
            lsum *= sc;
            if (lane < 16) scb[wave][lane] = sc;
            float4 s4 = *(const float4*)&scb[wave][g8 * 4];
            #pragma unroll
            for (int dt = 0; dt < 4; ++dt) {
                accO[dt][0] *= s4.x; accO[dt][1] *= s4.y;
                accO[dt][2] *= s4.z; accO[dt][3] *= s4.w;
            }
        }

        // ---------- P = exp2(S - m), packed b64 store, in-lane tree sum ----------
        #pragma unroll
        for (int jt = 0; jt < 4; ++jt)
            #pragma unroll
            for (int reg = 0; reg < 4; ++reg)
                sl[jt][reg] = exp2f(sl[jt][reg] - m);
        float ps = ((sl[0][0] + sl[0][1]) + (sl[0][2] + sl[0][3]))
                 + ((sl[1][0] + sl[1][1]) + (sl[1][2] + sl[1][3]))
                 + ((sl[2][0] + sl[2][1]) + (sl[2][2] + sl[2][3]))
                 + ((sl[3][0] + sl[3][1]) + (sl[3][2] + sl[3][3]));
        short* pP = &pun[wave][0];               // overwrites bdT (reads done, same wave)
        #pragma unroll
        for (int jt = 0; jt < 4; ++jt) {
            const int ch = (jt * 2 + (g8 >> 1)) ^ r7;
            uint2 pkd;
            pkd.x = pk2(sl[jt][0], sl[jt][1]);
            pkd.y = pk2(sl[jt][2], sl[jt][3]);
            *(uint2*)&pP[row16 * 64 + ch * 8 + (g8 & 1) * 4] = pkd;
        }
        ps += __shfl_xor(ps, 16, 64);
        ps += __shfl_xor(ps, 32, 64);
        lsum += ps;

        // ---------- PV: O += P @ V from Vl[cur] ----------
        __builtin_amdgcn_s_setprio(1);
        #pragma unroll
        for (int ks2 = 0; ks2 < 2; ++ks2) {
            short8 pf = *(const short8*)&pP[row16 * 64 + (((ks2 * 4 + g8) ^ r7) * 8)];
            #pragma unroll
            for (int dt = 0; dt < 4; ++dt) {
                const short* vp = &Vl[cur][dt * 16 + row16][(((ks2 * 4 + g8) ^ r7) * 8)];
                accO[dt] = MFMA16(pf, *(const short8*)vp, accO[dt]);
            }
        }
        __builtin_amdgcn_s_setprio(0);

        __syncthreads();   // drains staging: Kl[nxt]/Vl[nxt]/Rl-new valid for s+1
        cur = nxt;
    }

    // ---- epilogue: broadcast lsum to accO orientation, store ----
    if (lane < 16) scb[wave][lane] = lsum;
    float4 l4 = *(const float4*)&scb[wave][g8 * 4];
    float rl4[4] = {1.f / l4.x, 1.f / l4.y, 1.f / l4.z, 1.f / l4.w};
    #pragma unroll
    for (int dt = 0; dt < 4; ++dt)
        #pragma unroll
        for (int reg = 0; reg < 4; ++reg) {
            size_t o = ((size_t)(i0w + g8 * 4 + reg) * 2 + b) * D_MODELC + n * 64 + dt * 16 + row16;
            av[o] = (short)f2bf(accO[dt][reg] * rl4[reg]);
        }
}

// ---------------------------------------------------------------------------
// Residual + bias + LayerNorm: x = w + bf(p0) + bf(p1) + bo
// ---------------------------------------------------------------------------
__global__ __launch_bounds__(256) void ln_kernel(
    const float* __restrict__ w, const short* __restrict__ p0,
    const short* __restrict__ p1, const float* __restrict__ bo,
    const float* __restrict__ g, const float* __restrict__ bb,
    float* __restrict__ out)
{
    __shared__ float red[2][4];
    const int row = blockIdx.x;
    const int lane = threadIdx.x & 63;
    const int wv = threadIdx.x >> 6;
    const size_t base = (size_t)row * D_MODELC;
    const int c = threadIdx.x * 4;

    float4 xw = *(const float4*)&w[base + c];
    ushort4 a0 = *(const ushort4*)&p0[base + c];
    ushort4 a1 = *(const ushort4*)&p1[base + c];
    float4 xb = *(const float4*)&bo[c];
    float x[4] = {xw.x + bf2f((short)a0.x) + bf2f((short)a1.x) + xb.x,
                  xw.y + bf2f((short)a0.y) + bf2f((short)a1.y) + xb.y,
                  xw.z + bf2f((short)a0.z) + bf2f((short)a1.z) + xb.z,
                  xw.w + bf2f((short)a0.w) + bf2f((short)a1.w) + xb.w};

    float sum = x[0] + x[1] + x[2] + x[3];
    float ssq = x[0]*x[0] + x[1]*x[1] + x[2]*x[2] + x[3]*x[3];
    #pragma unroll
    for (int off = 32; off > 0; off >>= 1) {
        sum += __shfl_xor(sum, off, 64);
        ssq += __shfl_xor(ssq, off, 64);
    }
    if (lane == 0) { red[0][wv] = sum; red[1][wv] = ssq; }
    __syncthreads();
    sum = red[0][0] + red[0][1] + red[0][2] + red[0][3];
    ssq = red[1][0] + red[1][1] + red[1][2] + red[1][3];

    const float mu = sum * (1.0f / D_MODELC);
    const float var = ssq * (1.0f / D_MODELC) - mu * mu;
    const float rstd = rsqrtf(var + LN_EPSC);

    float4 o;
    o.x = (x[0] - mu) * rstd * g[c] + bb[c];
    o.y = (x[1] - mu) * rstd * g[c+1] + bb[c+1];
    o.z = (x[2] - mu) * rstd * g[c+2] + bb[c+2];
    o.w = (x[3] - mu) * rstd * g[c+3] + bb[c+3];
    *(float4*)&out[base + c] = o;
}

// ---------------------------------------------------------------------------
extern "C" void kernel_launch(void* const* d_in, const int* in_sizes, int n_in,
                              void* d_out, int out_size, void* d_ws, size_t ws_size,
                              hipStream_t stream)
{
    const float* w    = (const float*)d_in[0];
    const float* r    = (const float*)d_in[1];
    const float* mems = (const float*)d_in[2];
    const float* rwb  = (const float*)d_in[3];
    const float* rrb  = (const float*)d_in[4];
    // d_in[5] = attn_mask — deterministic causal+mem pattern, handled analytically
    const float* Wq = (const float*)d_in[6];
    const float* bq = (const float*)d_in[7];
    const float* Wk = (const float*)d_in[8];
    const float* bk = (const float*)d_in[9];
    const float* Wv = (const float*)d_in[10];
    const float* bv = (const float*)d_in[11];
    const float* Wr = (const float*)d_in[12];
    const float* br = (const float*)d_in[13];
    const float* Wo = (const float*)d_in[14];
    const float* bo = (const float*)d_in[15];
    const float* ln_g = (const float*)d_in[16];
    const float* ln_b = (const float*)d_in[17];
    float* out = (float*)d_out;

    char* ws = (char*)d_ws;
    const size_t MB = 1ull << 20;
    short* cat_bf = (short*)(ws + 0 * MB);    // 8 MB
    short* r_bf   = (short*)(ws + 8 * MB);    // 4 MB
    short* Wq_t   = (short*)(ws + 12 * MB);   // dead after proj -> wo out0
    short* Wk_t   = (short*)(ws + 14 * MB);
    short* Wv_t   = (short*)(ws + 16 * MB);   // dead after proj -> wo out1
    short* Wr_t   = (short*)(ws + 18 * MB);
    short* Wo_t   = (short*)(ws + 20 * MB);   // needed until wo_gemm
    short* qw_bf  = (short*)(ws + 22 * MB);
    short* qr_bf  = (short*)(ws + 26 * MB);
    short* k_bf   = (short*)(ws + 30 * MB);   // 8 MB
    short* v_bf   = (short*)(ws + 38 * MB);   // 8 MB
    short* rk_bf  = (short*)(ws + 46 * MB);
    short* vt     = (short*)(ws + 50 * MB);   // 8 MB
    short* av_bf  = (short*)(ws + 58 * MB);
    short* wo0    = Wq_t;                     // 4 MB (12..16)
    short* wo1    = Wv_t;                     // 4 MB (16..20)

    dim3 blk(256);

    // fused casts + weight transposes
    prep_kernel<<<dim3(16, 16, 17), blk, 0, stream>>>(
        mems, w, r, Wq, Wk, Wv, Wr, Wo,
        cat_bf, r_bf, Wq_t, Wk_t, Wv_t, Wr_t, Wo_t);

    // fused projections (K, V, Q->qw/qr scaled, RK)
    proj_gemm_kernel<<<dim3(8, 96), blk, 0, stream>>>(
        cat_bf, r_bf, Wq_t, Wk_t, Wv_t, Wr_t,
        bq, bk, bv, br, rwb, rrb,
        qw_bf, qr_bf, k_bf, v_bf, rk_bf);

    // V transpose
    vtrans_kernel<<<dim3(32, 32), blk, 0, stream>>>(v_bf, vt);

    // attention (round-8 structure): grid 512
    attn_mfma_kernel<<<dim3(16, 32), blk, 0, stream>>>(
        qw_bf, qr_bf, k_bf, rk_bf, vt, av_bf);

    // output projection split-K (bf16 partials; summed + bias in LN)
    wo_gemm_kernel<<<dim3(8, 16, 2), blk, 0, stream>>>(av_bf, Wo_t, wo0, wo1);

    // LN(w + wo0 + wo1 + bo)
    ln_kernel<<<dim3(2048), blk, 0, stream>>>(w, wo0, wo1, bo, ln_g, ln_b, out);
}

// Round 13
// 149.531 us; speedup vs baseline: 1.1719x; 1.0177x over previous
//
#include <hip/hip_runtime.h>
#include <math.h>

#define N_HEADC 16
#define D_MODELC 1024
#define D_HEADC 64
#define QLENC 1024
#define BSZC 2
#define MEMLENC 1024
#define KLENC 2048
#define SCALEC 0.125f
#define SL2C 0.18033688011112042f   // SCALE * log2(e)
#define LN_EPSC 1e-5f
#define RINGC 192

typedef __attribute__((ext_vector_type(8))) short short8;
typedef __attribute__((ext_vector_type(4))) float f32x4;

#define MFMA16(a, b, c) __builtin_amdgcn_mfma_f32_16x16x32_bf16((a), (b), (c), 0, 0, 0)

__device__ inline unsigned short f2bf(float x) {
    union { float f; unsigned int u; } c; c.f = x;
    unsigned int r = c.u + 0x7FFFu + ((c.u >> 16) & 1u);
    return (unsigned short)(r >> 16);
}
__device__ inline unsigned int pk2(float a, float b) { // 2xbf16 trunc pack
    union { float f; unsigned int u; } x, y; x.f = a; y.f = b;
    return (x.u >> 16) | (y.u & 0xFFFF0000u);
}
__device__ inline float bf2f(short s) {
    union { unsigned int u; float f; } c; c.u = ((unsigned int)(unsigned short)s) << 16;
    return c.f;
}

// async global->LDS, 16B per lane; lds dest = wave-uniform base + lane*16
__device__ __forceinline__ void load_lds16(const short* g, short* l) {
    __builtin_amdgcn_global_load_lds(
        (const __attribute__((address_space(1))) void*)g,
        (__attribute__((address_space(3))) void*)l,
        16, 0, 0);
}

// ---------------------------------------------------------------------------
// Fused prep: z<5 -> transpose+cast W_z; z>=5 -> flat bf16 casts (cat, r)
// grid (16,16,17)
// ---------------------------------------------------------------------------
__global__ __launch_bounds__(256) void prep_kernel(
    const float* __restrict__ mems, const float* __restrict__ wIn,
    const float* __restrict__ rIn,
    const float* __restrict__ W0, const float* __restrict__ W1,
    const float* __restrict__ W2, const float* __restrict__ W3,
    const float* __restrict__ W4,
    short* __restrict__ cat_bf, short* __restrict__ r_bf,
    short* __restrict__ D0, short* __restrict__ D1, short* __restrict__ D2,
    short* __restrict__ D3, short* __restrict__ D4)
{
    __shared__ short tile[64][72];
    const int z = blockIdx.z;
    const int t = threadIdx.x;

    if (z >= 5) {
        int lb = (z - 5) * 256 + blockIdx.y * 16 + blockIdx.x;
        int idx = (lb * 256 + t) * 8;
        const float* src; short* dst;
        if (idx < 4194304) {            // cat = [mems(2M); w(2M)]
            src = (idx < 2097152) ? (mems + idx) : (wIn + idx - 2097152);
            dst = cat_bf + idx;
        } else {
            src = rIn + (idx - 4194304);
            dst = r_bf + (idx - 4194304);
        }
        short8 o;
        #pragma unroll
        for (int e = 0; e < 8; ++e) o[e] = (short)f2bf(src[e]);
        *(short8*)dst = o;
        return;
    }

    const float* W; short* D;
    switch (z) {
        case 0: W = W0; D = D0; break;
        case 1: W = W1; D = D1; break;
        case 2: W = W2; D = D2; break;
        case 3: W = W3; D = D3; break;
        default: W = W4; D = D4; break;
    }
    const int n0 = blockIdx.x * 64, k0 = blockIdx.y * 64;
    #pragma unroll
    for (int it = 0; it < 2; ++it) {
        int idx = t + it * 256;
        int kl = idx >> 3, c8 = idx & 7;
        const float* src = W + (size_t)(k0 + kl) * D_MODELC + n0 + c8 * 8;
        short8 s;
        #pragma unroll
        for (int e = 0; e < 8; ++e) s[e] = (short)f2bf(src[e]);
        *(short8*)&tile[kl][c8 * 8] = s;
    }
    __syncthreads();
    #pragma unroll
    for (int it = 0; it < 2; ++it) {
        int idx = t + it * 256;
        int nl = idx >> 3, c8 = idx & 7;
        short8 s;
        #pragma unroll
        for (int e = 0; e < 8; ++e) s[e] = tile[c8 * 8 + e][nl];
        *(short8*)(D + (size_t)(n0 + nl) * D_MODELC + k0 + c8 * 8) = s;
    }
}

// ---------------------------------------------------------------------------
// V transpose: v_bf [4096][1024] (row=j*2+b, col=n*64+d) -> vt [b][n][d=64][j=2048]
// ---------------------------------------------------------------------------
__global__ __launch_bounds__(256) void vtrans_kernel(
    const short* __restrict__ v_bf, short* __restrict__ vt)
{
    __shared__ short tile[64][72];
    const int t = threadIdx.x;
    const int j0 = blockIdx.x * 64;
    const int bn = blockIdx.y;
    const int b = bn & 1, n = bn >> 1;
    #pragma unroll
    for (int it = 0; it < 2; ++it) {
        int idx = t + it * 256;
        int jl = idx >> 3, c8 = idx & 7;
        short8 s = *(const short8*)(v_bf + ((size_t)(j0 + jl) * 2 + b) * D_MODELC + n * 64 + c8 * 8);
        *(short8*)&tile[jl][c8 * 8] = s;
    }
    __syncthreads();
    #pragma unroll
    for (int it = 0; it < 2; ++it) {
        int idx = t + it * 256;
        int dl = idx >> 3, c8 = idx & 7;
        short8 s;
        #pragma unroll
        for (int e = 0; e < 8; ++e) s[e] = tile[c8 * 8 + e][dl];
        *(short8*)(vt + ((size_t)(b * 16 + n) * 64 + dl) * (size_t)KLENC + j0 + c8 * 8) = s;
    }
}

// ---------------------------------------------------------------------------
// Fused projection GEMMs (K, V, Q, RK) via global_load_lds, 128x128 tile, BK=32.
// LDS tiles XOR-swizzled (round-8 proven structure, verbatim loop).
// ---------------------------------------------------------------------------
__global__ __launch_bounds__(256, 3) void proj_gemm_kernel(
    const short* __restrict__ cat, const short* __restrict__ rin,
    const short* __restrict__ WqT, const short* __restrict__ WkT,
    const short* __restrict__ WvT, const short* __restrict__ WrT,
    const float* __restrict__ bq, const float* __restrict__ bk,
    const float* __restrict__ bv, const float* __restrict__ br,
    const float* __restrict__ rwb, const float* __restrict__ rrb,
    short* __restrict__ qw, short* __restrict__ qr,
    short* __restrict__ kb, short* __restrict__ vb, short* __restrict__ rk)
{
    __shared__ short As[128][32];
    __shared__ short Bs[128][32];

    const int lin = blockIdx.y * 8 + blockIdx.x;        // 0..767
    const int sw  = (lin & 7) * 96 + (lin >> 3);        // XCD-contiguous
    const int bx  = sw & 7;
    const int by  = sw >> 3;

    const short* A; const short* Bt; const float* bias; int yt, mode;
    if (by < 32)      { A = cat;                         Bt = WkT; bias = bk; yt = by;      mode = 0; }
    else if (by < 64) { A = cat;                         Bt = WvT; bias = bv; yt = by - 32; mode = 1; }
    else if (by < 80) { A = cat + (size_t)2048 * 1024;   Bt = WqT; bias = bq; yt = by - 64; mode = 2; }
    else              { A = rin;                         Bt = WrT; bias = br; yt = by - 80; mode = 3; }

    const int row0 = yt * 128, col0 = bx * 128;
    const int t = threadIdx.x;
    const int lane = t & 63, wid = t >> 6;
    const int row16 = lane & 15, g8 = lane >> 4;
    const int wr = wid >> 1, wc = wid & 1;

    f32x4 acc[4][4];
    #pragma unroll
    for (int m = 0; m < 4; ++m)
        #pragma unroll
        for (int nn = 0; nn < 4; ++nn)
            acc[m][nn] = (f32x4){0.f, 0.f, 0.f, 0.f};

    short* AsB = &As[0][0] + wid * 1024;
    short* BsB = &Bs[0][0] + wid * 1024;
    const int srow4 = lane >> 2;
    const int cs4 = (lane & 3) ^ ((lane >> 3) & 3);     // swizzled source chunk
    const short* Ag = A  + (size_t)(row0 + wid * 32 + srow4) * D_MODELC + cs4 * 8;
    const short* Bg = Bt + (size_t)(col0 + wid * 32 + srow4) * D_MODELC + cs4 * 8;
    const int xc2 = (row16 >> 1) & 3;                   // read-side xor

    for (int k0 = 0; k0 < D_MODELC; k0 += 32) {
        load_lds16(Ag + k0,              AsB);
        load_lds16(Ag + k0 + 16 * 1024,  AsB + 512);
        load_lds16(Bg + k0,              BsB);
        load_lds16(Bg + k0 + 16 * 1024,  BsB + 512);
        __syncthreads();
        short8 af[4], bfr[4];
        #pragma unroll
        for (int m = 0; m < 4; ++m)
            af[m] = *(const short8*)&As[wr * 64 + m * 16 + row16][(g8 ^ xc2) * 8];
        #pragma unroll
        for (int nn = 0; nn < 4; ++nn)
            bfr[nn] = *(const short8*)&Bs[wc * 64 + nn * 16 + row16][(g8 ^ xc2) * 8];
        #pragma unroll
        for (int m = 0; m < 4; ++m)
            #pragma unroll
            for (int nn = 0; nn < 4; ++nn)
                acc[m][nn] = MFMA16(af[m], bfr[nn], acc[m][nn]);
        __syncthreads();
    }

    float bvv[4], w1[4], w2[4];
    #pragma unroll
    for (int nn = 0; nn < 4; ++nn) {
        int c = col0 + wc * 64 + nn * 16 + row16;
        bvv[nn] = bias[c];
        w1[nn] = rwb[c];
        w2[nn] = rrb[c];
    }
    if (mode == 2) {
        #pragma unroll
        for (int m = 0; m < 4; ++m)
            #pragma unroll
            for (int nn = 0; nn < 4; ++nn) {
                int c = col0 + wc * 64 + nn * 16 + row16;
                #pragma unroll
                for (int reg = 0; reg < 4; ++reg) {
                    int r = row0 + wr * 64 + m * 16 + g8 * 4 + reg;
                    float v = acc[m][nn][reg] + bvv[nn];
                    // fold SCALE*log2(e) into q-side operands for attn
                    qw[(size_t)r * D_MODELC + c] = (short)f2bf((v + w1[nn]) * SL2C);
                    qr[(size_t)r * D_MODELC + c] = (short)f2bf((v + w2[nn]) * SL2C);
                }
            }
    } else {
        short* C = (mode == 0) ? kb : (mode == 1) ? vb : rk;
        #pragma unroll
        for (int m = 0; m < 4; ++m)
            #pragma unroll
            for (int nn = 0; nn < 4; ++nn) {
                int c = col0 + wc * 64 + nn * 16 + row16;
                #pragma unroll
                for (int reg = 0; reg < 4; ++reg) {
                    int r = row0 + wr * 64 + m * 16 + g8 * 4 + reg;
                    C[(size_t)r * D_MODELC + c] = (short)f2bf(acc[m][nn][reg] + bvv[nn]);
                }
            }
    }
}

// ---------------------------------------------------------------------------
// Wo GEMM, split-K=2: bf16 partials (summed + bias in LN). Round-8 loop.
// ---------------------------------------------------------------------------
__global__ __launch_bounds__(256, 3) void wo_gemm_kernel(
    const short* __restrict__ A, const short* __restrict__ Bt,
    short* __restrict__ out0, short* __restrict__ out1)
{
    __shared__ short As[128][32];
    __shared__ short Bs[128][32];
    const int kz = blockIdx.z;
    short* C = kz ? out1 : out0;
    const int row0 = blockIdx.y * 128, col0 = blockIdx.x * 128;
    const int t = threadIdx.x;
    const int lane = t & 63, wid = t >> 6;
    const int row16 = lane & 15, g8 = lane >> 4;
    const int wr = wid >> 1, wc = wid & 1;

    f32x4 acc[4][4];
    #pragma unroll
    for (int m = 0; m < 4; ++m)
        #pragma unroll
        for (int nn = 0; nn < 4; ++nn)
            acc[m][nn] = (f32x4){0.f, 0.f, 0.f, 0.f};

    short* AsB = &As[0][0] + wid * 1024;
    short* BsB = &Bs[0][0] + wid * 1024;
    const int srow4 = lane >> 2;
    const int cs4 = (lane & 3) ^ ((lane >> 3) & 3);
    const short* Ag = A  + (size_t)(row0 + wid * 32 + srow4) * D_MODELC + cs4 * 8;
    const short* Bg = Bt + (size_t)(col0 + wid * 32 + srow4) * D_MODELC + cs4 * 8;
    const int xc2 = (row16 >> 1) & 3;

    const int kbase = kz * 512;
    for (int k0 = kbase; k0 < kbase + 512; k0 += 32) {
        load_lds16(Ag + k0,             AsB);
        load_lds16(Ag + k0 + 16 * 1024, AsB + 512);
        load_lds16(Bg + k0,             BsB);
        load_lds16(Bg + k0 + 16 * 1024, BsB + 512);
        __syncthreads();
        short8 af[4], bfr[4];
        #pragma unroll
        for (int m = 0; m < 4; ++m)
            af[m] = *(const short8*)&As[wr * 64 + m * 16 + row16][(g8 ^ xc2) * 8];
        #pragma unroll
        for (int nn = 0; nn < 4; ++nn)
            bfr[nn] = *(const short8*)&Bs[wc * 64 + nn * 16 + row16][(g8 ^ xc2) * 8];
        #pragma unroll
        for (int m = 0; m < 4; ++m)
            #pragma unroll
            for (int nn = 0; nn < 4; ++nn)
                acc[m][nn] = MFMA16(af[m], bfr[nn], acc[m][nn]);
        __syncthreads();
    }

    #pragma unroll
    for (int m = 0; m < 4; ++m)
        #pragma unroll
        for (int nn = 0; nn < 4; ++nn) {
            int c = col0 + wc * 64 + nn * 16 + row16;
            #pragma unroll
            for (int reg = 0; reg < 4; ++reg) {
                int r = row0 + wr * 64 + m * 16 + g8 * 4 + reg;
                C[(size_t)r * D_MODELC + c] = (short)f2bf(acc[m][nn][reg]);
            }
        }
}

// ---------------------------------------------------------------------------
// LDS-staged MFMA flash attention, S^T softmax (round-8/12 structure) with
// LAZY cross-lane reduction: per-step row-max/row-sum shuffles removed.
// lsum is a per-lane partial (reduced once in epilogue); the defer-max
// trigger uses only the in-lane partial max; the 2-shuffle row-max runs
// only on the rare rescale path. m stays row-uniform by construction.
// ---------------------------------------------------------------------------
__global__ __launch_bounds__(256, 2) void attn_mfma_kernel(
    const short* __restrict__ qw, const short* __restrict__ qr,
    const short* __restrict__ kb, const short* __restrict__ rkb,
    const short* __restrict__ vt, short* __restrict__ av)
{
    __shared__ short Kl[2][64][64];      // 16 KB (dbuf)
    __shared__ short Vl[2][64][64];      // 16 KB (dbuf, [d][j])
    __shared__ short Rl[RINGC][64];      // 24 KB (rk ring, row = jr % 192)
    __shared__ short pun[4][1376];       // 11 KB: bdT [16][84] alias P [16][64]
    __shared__ float scb[4][16];         // sc / lsum broadcast

    const int wave = threadIdx.x >> 6, lane = threadIdx.x & 63;
    const int row16 = lane & 15, g8 = lane >> 4;
    const int srow = lane >> 3, chk = lane & 7;
    const int swz = srow & 7;            // staging source-chunk xor

    // balanced + XCD-contiguous remap: CU gets ic and 15-ic (pair sum uniform)
    const int lin = blockIdx.y * 16 + blockIdx.x;   // 0..511
    const int xcd = lin & 7;
    const int u   = lin >> 3;                        // 0..63
    const int v   = u & 31;
    const int bn  = xcd * 4 + (v >> 3);
    const int tt  = v & 7;
    const int ic  = (u >> 5) ? (15 - tt) : tt;
    const int b = bn & 1, n = bn >> 1;
    const int i0 = ic * 64;
    const int i0w = i0 + wave * 16;

    // Q fragments (row = i0w+row16, k = ks*32 + g8*8 + e), pre-scaled by SL2C
    short8 qwf[2], qrf[2];
    #pragma unroll
    for (int ks = 0; ks < 2; ++ks) {
        size_t off = ((size_t)(i0w + row16) * 2 + b) * D_MODELC + n * 64 + ks * 32 + g8 * 8;
        qwf[ks] = *(const short8*)(qw + off);
        qrf[ks] = *(const short8*)(qr + off);
    }

    // ---- prologue: stage K(0), V(0), rk window(0) = [960-i0, 1088-i0) ----
    #pragma unroll
    for (int t = 0; t < 2; ++t) {
        int rr = wave * 16 + t * 8;
        int j  = rr + srow;
        int cs = chk ^ swz;
        load_lds16(kb + ((size_t)j * 2 + b) * D_MODELC + n * 64 + cs * 8, &Kl[0][rr][0]);
        load_lds16(vt + ((size_t)((b * 16 + n) * 64 + rr + srow)) * KLENC + cs * 8,
                   &Vl[0][rr][0]);
    }
    {
        const int p0 = 960 - i0;                  // multiple of 8 (>=0)
        #pragma unroll
        for (int t = 0; t < 4; ++t) {
            int jrb_ = p0 + wave * 32 + t * 8;
            int slotb = jrb_ % RINGC;
            int jr = jrb_ + srow;
            int jc = jr < KLENC ? jr : KLENC - 1;
            int cs = chk ^ swz;
            load_lds16(rkb + (size_t)jc * D_MODELC + n * 64 + cs * 8, &Rl[slotb][0]);
        }
    }

    f32x4 accO[4];
    #pragma unroll
    for (int dt = 0; dt < 4; ++dt) accO[dt] = (f32x4){0.f, 0.f, 0.f, 0.f};
    float m = -INFINITY;                 // row-uniform running max (log2 domain)
    float lsum = 0.f;                    // PER-LANE partial sum (reduced at end)

    const int T = (i0 + 63 + MEMLENC + 64) >> 6;
    const int r7 = row16 & 7;

    __syncthreads();

    int cur = 0;
    for (int s = 0; s < T; ++s) {
        const int j0 = s * 64;
        const int nxt = cur ^ 1;

        // ---------- issue async staging for step s+1 ----------
        #pragma unroll
        for (int t = 0; t < 2; ++t) {             // K(s+1)
            int rr = wave * 16 + t * 8;
            int j  = j0 + 64 + rr + srow;
            if (j > KLENC - 1) j = KLENC - 1;
            int cs = chk ^ swz;
            load_lds16(kb + ((size_t)j * 2 + b) * D_MODELC + n * 64 + cs * 8, &Kl[nxt][rr][0]);
        }
        {
            const int nb = j0 + 1088 - i0;        // new rk rows for window(s+1)
            #pragma unroll
            for (int t = 0; t < 2; ++t) {
                int jrb_ = nb + wave * 16 + t * 8;
                int slotb = jrb_ % RINGC;
                int jr = jrb_ + srow;
                int jc = jr < KLENC ? jr : KLENC - 1;
                int cs = chk ^ swz;
                load_lds16(rkb + (size_t)jc * D_MODELC + n * 64 + cs * 8, &Rl[slotb][0]);
            }
        }
        {
            const int jsrc = (j0 + 64 <= KLENC - 64) ? (j0 + 64) : (KLENC - 64);
            #pragma unroll
            for (int t = 0; t < 2; ++t) {         // V(s+1), d-major
                int rr = wave * 16 + t * 8;
                int cs = chk ^ swz;
                load_lds16(vt + ((size_t)((b * 16 + n) * 64 + rr + srow)) * KLENC + jsrc + cs * 8,
                           &Vl[nxt][rr][0]);
            }
        }

        // ---------- AC^T = MFMA(K, Qw): lane holds j=g8*4+reg(+jt*16), i=row16 ----------
        __builtin_amdgcn_s_setprio(1);
        f32x4 st[4];
        #pragma unroll
        for (int jt = 0; jt < 4; ++jt) {
            st[jt] = (f32x4){0.f, 0.f, 0.f, 0.f};
            const short* kr = &Kl[cur][jt * 16 + row16][0];
            st[jt] = MFMA16(*(const short8*)(kr + ((g8 ^ r7) * 8)),       qwf[0], st[jt]);
            st[jt] = MFMA16(*(const short8*)(kr + (((4 + g8) ^ r7) * 8)), qwf[1], st[jt]);
        }

        // ---------- BD^T over jr window from ring; bdT[i][jr_loc] packed b64 ----------
        const int jrb_w = j0 - i0w + 1008;
        const int sb = jrb_w % RINGC;
        short* bdT = &pun[wave][0];               // [16][84]
        #pragma unroll
        for (int rt = 0; rt < 5; ++rt) {
            int rsl = sb + rt * 16 + row16;
            if (rsl >= RINGC) rsl -= RINGC;
            const short* rr = &Rl[rsl][0];
            f32x4 bd = (f32x4){0.f, 0.f, 0.f, 0.f};
            bd = MFMA16(*(const short8*)(rr + ((g8 ^ r7) * 8)),       qrf[0], bd);
            bd = MFMA16(*(const short8*)(rr + (((4 + g8) ^ r7) * 8)), qrf[1], bd);
            uint2 wv;
            wv.x = pk2(bd[0], bd[1]);
            wv.y = pk2(bd[2], bd[3]);
            *(uint2*)&bdT[row16 * 84 + rt * 16 + g8 * 4] = wv;
        }
        __builtin_amdgcn_s_setprio(0);

        // ---------- combine (+mask only on tail steps; scale pre-folded) ----------
        float sl[4][4];
        if (j0 + 63 <= i0w + MEMLENC) {
            #pragma unroll
            for (int jt = 0; jt < 4; ++jt)
                #pragma unroll
                for (int reg = 0; reg < 4; ++reg) {
                    const int jl = jt * 16 + g8 * 4 + reg;
                    sl[jt][reg] = st[jt][reg] + bf2f(bdT[row16 * 84 + jl + 15 - row16]);
                }
        } else {
            #pragma unroll
            for (int jt = 0; jt < 4; ++jt)
                #pragma unroll
                for (int reg = 0; reg < 4; ++reg) {
                    const int jl = jt * 16 + g8 * 4 + reg;
                    float vv = st[jt][reg] + bf2f(bdT[row16 * 84 + jl + 15 - row16]);
                    sl[jt][reg] = (j0 + jl > i0w + row16 + MEMLENC) ? -INFINITY : vv;
                }
        }

        // ---------- in-lane max tree (no cross-lane shuffles on fast path) ----------
        float mx0 = fmaxf(fmaxf(sl[0][0], sl[0][1]), fmaxf(sl[0][2], sl[0][3]));
        float mx1 = fmaxf(fmaxf(sl[1][0], sl[1][1]), fmaxf(sl[1][2], sl[1][3]));
        float mx2 = fmaxf(fmaxf(sl[2][0], sl[2][1]), fmaxf(sl[2][2], sl[2][3]));
        float mx3 = fmaxf(fmaxf(sl[3][0], sl[3][1]), fmaxf(sl[3][2], sl[3][3]));
        float mx = fmaxf(fmaxf(mx0, mx1), fmaxf(mx2, mx3));

        // ---------- defer-max rescale (rare; row-max shuffles only here) ----------
        if (__any(mx > m + 8.f)) {
            float mxr = mx;
            mxr = fmaxf(mxr, __shfl_xor(mxr, 16, 64));
            mxr = fmaxf(mxr, __shfl_xor(mxr, 32, 64));   // row max (row-uniform)
            float mn = fmaxf(m, mxr);
            float sc = exp2f(m - mn);            // first step: exp2(-inf)=0
            m = mn;
            lsum *= sc;
            if (lane < 16) scb[wave][lane] = sc;
            float4 s4 = *(const float4*)&scb[wave][g8 * 4];
            #pragma unroll
            for (int dt = 0; dt < 4; ++dt) {
                accO[dt][0] *= s4.x; accO[dt][1] *= s4.y;
                accO[dt][2] *= s4.z; accO[dt][3] *= s4.w;
            }
        }

        // ---------- P = exp2(S - m), packed b64 store, per-lane partial sum ----------
        #pragma unroll
        for (int jt = 0; jt < 4; ++jt)
            #pragma unroll
            for (int reg = 0; reg < 4; ++reg)
                sl[jt][reg] = exp2f(sl[jt][reg] - m);
        float ps = ((sl[0][0] + sl[0][1]) + (sl[0][2] + sl[0][3]))
                 + ((sl[1][0] + sl[1][1]) + (sl[1][2] + sl[1][3]))
                 + ((sl[2][0] + sl[2][1]) + (sl[2][2] + sl[2][3]))
                 + ((sl[3][0] + sl[3][1]) + (sl[3][2] + sl[3][3]));
        short* pP = &pun[wave][0];               // overwrites bdT (reads done, same wave)
        #pragma unroll
        for (int jt = 0; jt < 4; ++jt) {
            const int ch = (jt * 2 + (g8 >> 1)) ^ r7;
            uint2 pkd;
            pkd.x = pk2(sl[jt][0], sl[jt][1]);
            pkd.y = pk2(sl[jt][2], sl[jt][3]);
            *(uint2*)&pP[row16 * 64 + ch * 8 + (g8 & 1) * 4] = pkd;
        }
        lsum += ps;                              // per-lane partial; no shuffles

        // ---------- PV: O += P @ V from Vl[cur] ----------
        __builtin_amdgcn_s_setprio(1);
        #pragma unroll
        for (int ks2 = 0; ks2 < 2; ++ks2) {
            short8 pf = *(const short8*)&pP[row16 * 64 + (((ks2 * 4 + g8) ^ r7) * 8)];
            #pragma unroll
            for (int dt = 0; dt < 4; ++dt) {
                const short* vp = &Vl[cur][dt * 16 + row16][(((ks2 * 4 + g8) ^ r7) * 8)];
                accO[dt] = MFMA16(pf, *(const short8*)vp, accO[dt]);
            }
        }
        __builtin_amdgcn_s_setprio(0);

        __syncthreads();   // drains staging: Kl[nxt]/Vl[nxt]/Rl-new valid for s+1
        cur = nxt;
    }

    // ---- epilogue: reduce per-lane lsum across the row's 4 lanes, store ----
    lsum += __shfl_xor(lsum, 16, 64);
    lsum += __shfl_xor(lsum, 32, 64);
    if (lane < 16) scb[wave][lane] = lsum;
    float4 l4 = *(const float4*)&scb[wave][g8 * 4];
    float rl4[4] = {1.f / l4.x, 1.f / l4.y, 1.f / l4.z, 1.f / l4.w};
    #pragma unroll
    for (int dt = 0; dt < 4; ++dt)
        #pragma unroll
        for (int reg = 0; reg < 4; ++reg) {
            size_t o = ((size_t)(i0w + g8 * 4 + reg) * 2 + b) * D_MODELC + n * 64 + dt * 16 + row16;
            av[o] = (short)f2bf(accO[dt][reg] * rl4[reg]);
        }
}

// ---------------------------------------------------------------------------
// Residual + bias + LayerNorm: x = w + bf(p0) + bf(p1) + bo
// ---------------------------------------------------------------------------
__global__ __launch_bounds__(256) void ln_kernel(
    const float* __restrict__ w, const short* __restrict__ p0,
    const short* __restrict__ p1, const float* __restrict__ bo,
    const float* __restrict__ g, const float* __restrict__ bb,
    float* __restrict__ out)
{
    __shared__ float red[2][4];
    const int row = blockIdx.x;
    const int lane = threadIdx.x & 63;
    const int wv = threadIdx.x >> 6;
    const size_t base = (size_t)row * D_MODELC;
    const int c = threadIdx.x * 4;

    float4 xw = *(const float4*)&w[base + c];
    ushort4 a0 = *(const ushort4*)&p0[base + c];
    ushort4 a1 = *(const ushort4*)&p1[base + c];
    float4 xb = *(const float4*)&bo[c];
    float x[4] = {xw.x + bf2f((short)a0.x) + bf2f((short)a1.x) + xb.x,
                  xw.y + bf2f((short)a0.y) + bf2f((short)a1.y) + xb.y,
                  xw.z + bf2f((short)a0.z) + bf2f((short)a1.z) + xb.z,
                  xw.w + bf2f((short)a0.w) + bf2f((short)a1.w) + xb.w};

    float sum = x[0] + x[1] + x[2] + x[3];
    float ssq = x[0]*x[0] + x[1]*x[1] + x[2]*x[2] + x[3]*x[3];
    #pragma unroll
    for (int off = 32; off > 0; off >>= 1) {
        sum += __shfl_xor(sum, off, 64);
        ssq += __shfl_xor(ssq, off, 64);
    }
    if (lane == 0) { red[0][wv] = sum; red[1][wv] = ssq; }
    __syncthreads();
    sum = red[0][0] + red[0][1] + red[0][2] + red[0][3];
    ssq = red[1][0] + red[1][1] + red[1][2] + red[1][3];

    const float mu = sum * (1.0f / D_MODELC);
    const float var = ssq * (1.0f / D_MODELC) - mu * mu;
    const float rstd = rsqrtf(var + LN_EPSC);

    float4 o;
    o.x = (x[0] - mu) * rstd * g[c] + bb[c];
    o.y = (x[1] - mu) * rstd * g[c+1] + bb[c+1];
    o.z = (x[2] - mu) * rstd * g[c+2] + bb[c+2];
    o.w = (x[3] - mu) * rstd * g[c+3] + bb[c+3];
    *(float4*)&out[base + c] = o;
}

// ---------------------------------------------------------------------------
extern "C" void kernel_launch(void* const* d_in, const int* in_sizes, int n_in,
                              void* d_out, int out_size, void* d_ws, size_t ws_size,
                              hipStream_t stream)
{
    const float* w    = (const float*)d_in[0];
    const float* r    = (const float*)d_in[1];
    const float* mems = (const float*)d_in[2];
    const float* rwb  = (const float*)d_in[3];
    const float* rrb  = (const float*)d_in[4];
    // d_in[5] = attn_mask — deterministic causal+mem pattern, handled analytically
    const float* Wq = (const float*)d_in[6];
    const float* bq = (const float*)d_in[7];
    const float* Wk = (const float*)d_in[8];
    const float* bk = (const float*)d_in[9];
    const float* Wv = (const float*)d_in[10];
    const float* bv = (const float*)d_in[11];
    const float* Wr = (const float*)d_in[12];
    const float* br = (const float*)d_in[13];
    const float* Wo = (const float*)d_in[14];
    const float* bo = (const float*)d_in[15];
    const float* ln_g = (const float*)d_in[16];
    const float* ln_b = (const float*)d_in[17];
    float* out = (float*)d_out;

    char* ws = (char*)d_ws;
    const size_t MB = 1ull << 20;
    short* cat_bf = (short*)(ws + 0 * MB);    // 8 MB
    short* r_bf   = (short*)(ws + 8 * MB);    // 4 MB
    short* Wq_t   = (short*)(ws + 12 * MB);   // dead after proj -> wo out0
    short* Wk_t   = (short*)(ws + 14 * MB);
    short* Wv_t   = (short*)(ws + 16 * MB);   // dead after proj -> wo out1
    short* Wr_t   = (short*)(ws + 18 * MB);
    short* Wo_t   = (short*)(ws + 20 * MB);   // needed until wo_gemm
    short* qw_bf  = (short*)(ws + 22 * MB);
    short* qr_bf  = (short*)(ws + 26 * MB);
    short* k_bf   = (short*)(ws + 30 * MB);   // 8 MB
    short* v_bf   = (short*)(ws + 38 * MB);   // 8 MB
    short* rk_bf  = (short*)(ws + 46 * MB);
    short* vt     = (short*)(ws + 50 * MB);   // 8 MB
    short* av_bf  = (short*)(ws + 58 * MB);
    short* wo0    = Wq_t;                     // 4 MB (12..16)
    short* wo1    = Wv_t;                     // 4 MB (16..20)

    dim3 blk(256);

    // fused casts + weight transposes
    prep_kernel<<<dim3(16, 16, 17), blk, 0, stream>>>(
        mems, w, r, Wq, Wk, Wv, Wr, Wo,
        cat_bf, r_bf, Wq_t, Wk_t, Wv_t, Wr_t, Wo_t);

    // fused projections (K, V, Q->qw/qr scaled, RK)
    proj_gemm_kernel<<<dim3(8, 96), blk, 0, stream>>>(
        cat_bf, r_bf, Wq_t, Wk_t, Wv_t, Wr_t,
        bq, bk, bv, br, rwb, rrb,
        qw_bf, qr_bf, k_bf, v_bf, rk_bf);

    // V transpose
    vtrans_kernel<<<dim3(32, 32), blk, 0, stream>>>(v_bf, vt);

    // attention (round-8 structure + lazy cross-lane reduction): grid 512
    attn_mfma_kernel<<<dim3(16, 32), blk, 0, stream>>>(
        qw_bf, qr_bf, k_bf, rk_bf, vt, av_bf);

    // output projection split-K (bf16 partials; summed + bias in LN)
    wo_gemm_kernel<<<dim3(8, 16, 2), blk, 0, stream>>>(av_bf, Wo_t, wo0, wo1);

    // LN(w + wo0 + wo1 + bo)
    ln_kernel<<<dim3(2048), blk, 0, stream>>>(w, wo0, wo1, bo, ln_g, ln_b, out);
}

// Round 14
// 149.135 us; speedup vs baseline: 1.1750x; 1.0027x over previous
//
#include <hip/hip_runtime.h>
#include <math.h>

#define N_HEADC 16
#define D_MODELC 1024
#define D_HEADC 64
#define QLENC 1024
#define BSZC 2
#define MEMLENC 1024
#define KLENC 2048
#define SCALEC 0.125f
#define SL2C 0.18033688011112042f   // SCALE * log2(e)
#define LN_EPSC 1e-5f
#define RINGC 192

typedef __attribute__((ext_vector_type(8))) short short8;
typedef __attribute__((ext_vector_type(4))) float f32x4;

#define MFMA16(a, b, c) __builtin_amdgcn_mfma_f32_16x16x32_bf16((a), (b), (c), 0, 0, 0)

__device__ inline unsigned short f2bf(float x) {
    union { float f; unsigned int u; } c; c.f = x;
    unsigned int r = c.u + 0x7FFFu + ((c.u >> 16) & 1u);
    return (unsigned short)(r >> 16);
}
__device__ inline unsigned int pk2(float a, float b) { // 2xbf16 trunc pack
    union { float f; unsigned int u; } x, y; x.f = a; y.f = b;
    return (x.u >> 16) | (y.u & 0xFFFF0000u);
}
__device__ inline float bf2f(short s) {
    union { unsigned int u; float f; } c; c.u = ((unsigned int)(unsigned short)s) << 16;
    return c.f;
}

// async global->LDS, 16B per lane; lds dest = wave-uniform base + lane*16
__device__ __forceinline__ void load_lds16(const short* g, short* l) {
    __builtin_amdgcn_global_load_lds(
        (const __attribute__((address_space(1))) void*)g,
        (__attribute__((address_space(3))) void*)l,
        16, 0, 0);
}

// ---------------------------------------------------------------------------
// Fused prep: z<5 -> transpose+cast W_z; z>=5 -> flat bf16 casts (cat, r)
// grid (16,16,17)
// ---------------------------------------------------------------------------
__global__ __launch_bounds__(256) void prep_kernel(
    const float* __restrict__ mems, const float* __restrict__ wIn,
    const float* __restrict__ rIn,
    const float* __restrict__ W0, const float* __restrict__ W1,
    const float* __restrict__ W2, const float* __restrict__ W3,
    const float* __restrict__ W4,
    short* __restrict__ cat_bf, short* __restrict__ r_bf,
    short* __restrict__ D0, short* __restrict__ D1, short* __restrict__ D2,
    short* __restrict__ D3, short* __restrict__ D4)
{
    __shared__ short tile[64][72];
    const int z = blockIdx.z;
    const int t = threadIdx.x;

    if (z >= 5) {
        int lb = (z - 5) * 256 + blockIdx.y * 16 + blockIdx.x;
        int idx = (lb * 256 + t) * 8;
        const float* src; short* dst;
        if (idx < 4194304) {            // cat = [mems(2M); w(2M)]
            src = (idx < 2097152) ? (mems + idx) : (wIn + idx - 2097152);
            dst = cat_bf + idx;
        } else {
            src = rIn + (idx - 4194304);
            dst = r_bf + (idx - 4194304);
        }
        short8 o;
        #pragma unroll
        for (int e = 0; e < 8; ++e) o[e] = (short)f2bf(src[e]);
        *(short8*)dst = o;
        return;
    }

    const float* W; short* D;
    switch (z) {
        case 0: W = W0; D = D0; break;
        case 1: W = W1; D = D1; break;
        case 2: W = W2; D = D2; break;
        case 3: W = W3; D = D3; break;
        default: W = W4; D = D4; break;
    }
    const int n0 = blockIdx.x * 64, k0 = blockIdx.y * 64;
    #pragma unroll
    for (int it = 0; it < 2; ++it) {
        int idx = t + it * 256;
        int kl = idx >> 3, c8 = idx & 7;
        const float* src = W + (size_t)(k0 + kl) * D_MODELC + n0 + c8 * 8;
        short8 s;
        #pragma unroll
        for (int e = 0; e < 8; ++e) s[e] = (short)f2bf(src[e]);
        *(short8*)&tile[kl][c8 * 8] = s;
    }
    __syncthreads();
    #pragma unroll
    for (int it = 0; it < 2; ++it) {
        int idx = t + it * 256;
        int nl = idx >> 3, c8 = idx & 7;
        short8 s;
        #pragma unroll
        for (int e = 0; e < 8; ++e) s[e] = tile[c8 * 8 + e][nl];
        *(short8*)(D + (size_t)(n0 + nl) * D_MODELC + k0 + c8 * 8) = s;
    }
}

// ---------------------------------------------------------------------------
// V transpose: v_bf [4096][1024] (row=j*2+b, col=n*64+d) -> vt [b][n][d=64][j=2048]
// ---------------------------------------------------------------------------
__global__ __launch_bounds__(256) void vtrans_kernel(
    const short* __restrict__ v_bf, short* __restrict__ vt)
{
    __shared__ short tile[64][72];
    const int t = threadIdx.x;
    const int j0 = blockIdx.x * 64;
    const int bn = blockIdx.y;
    const int b = bn & 1, n = bn >> 1;
    #pragma unroll
    for (int it = 0; it < 2; ++it) {
        int idx = t + it * 256;
        int jl = idx >> 3, c8 = idx & 7;
        short8 s = *(const short8*)(v_bf + ((size_t)(j0 + jl) * 2 + b) * D_MODELC + n * 64 + c8 * 8);
        *(short8*)&tile[jl][c8 * 8] = s;
    }
    __syncthreads();
    #pragma unroll
    for (int it = 0; it < 2; ++it) {
        int idx = t + it * 256;
        int dl = idx >> 3, c8 = idx & 7;
        short8 s;
        #pragma unroll
        for (int e = 0; e < 8; ++e) s[e] = tile[c8 * 8 + e][dl];
        *(short8*)(vt + ((size_t)(b * 16 + n) * 64 + dl) * (size_t)KLENC + j0 + c8 * 8) = s;
    }
}

// ---------------------------------------------------------------------------
// Fused projection GEMMs (K, V, Q, RK) via global_load_lds, 128x128 tile, BK=32.
// LDS tiles XOR-swizzled (round-8 proven structure, verbatim loop).
// ---------------------------------------------------------------------------
__global__ __launch_bounds__(256, 3) void proj_gemm_kernel(
    const short* __restrict__ cat, const short* __restrict__ rin,
    const short* __restrict__ WqT, const short* __restrict__ WkT,
    const short* __restrict__ WvT, const short* __restrict__ WrT,
    const float* __restrict__ bq, const float* __restrict__ bk,
    const float* __restrict__ bv, const float* __restrict__ br,
    const float* __restrict__ rwb, const float* __restrict__ rrb,
    short* __restrict__ qw, short* __restrict__ qr,
    short* __restrict__ kb, short* __restrict__ vb, short* __restrict__ rk)
{
    __shared__ short As[128][32];
    __shared__ short Bs[128][32];

    const int lin = blockIdx.y * 8 + blockIdx.x;        // 0..767
    const int sw  = (lin & 7) * 96 + (lin >> 3);        // XCD-contiguous
    const int bx  = sw & 7;
    const int by  = sw >> 3;

    const short* A; const short* Bt; const float* bias; int yt, mode;
    if (by < 32)      { A = cat;                         Bt = WkT; bias = bk; yt = by;      mode = 0; }
    else if (by < 64) { A = cat;                         Bt = WvT; bias = bv; yt = by - 32; mode = 1; }
    else if (by < 80) { A = cat + (size_t)2048 * 1024;   Bt = WqT; bias = bq; yt = by - 64; mode = 2; }
    else              { A = rin;                         Bt = WrT; bias = br; yt = by - 80; mode = 3; }

    const int row0 = yt * 128, col0 = bx * 128;
    const int t = threadIdx.x;
    const int lane = t & 63, wid = t >> 6;
    const int row16 = lane & 15, g8 = lane >> 4;
    const int wr = wid >> 1, wc = wid & 1;

    f32x4 acc[4][4];
    #pragma unroll
    for (int m = 0; m < 4; ++m)
        #pragma unroll
        for (int nn = 0; nn < 4; ++nn)
            acc[m][nn] = (f32x4){0.f, 0.f, 0.f, 0.f};

    short* AsB = &As[0][0] + wid * 1024;
    short* BsB = &Bs[0][0] + wid * 1024;
    const int srow4 = lane >> 2;
    const int cs4 = (lane & 3) ^ ((lane >> 3) & 3);     // swizzled source chunk
    const short* Ag = A  + (size_t)(row0 + wid * 32 + srow4) * D_MODELC + cs4 * 8;
    const short* Bg = Bt + (size_t)(col0 + wid * 32 + srow4) * D_MODELC + cs4 * 8;
    const int xc2 = (row16 >> 1) & 3;                   // read-side xor

    for (int k0 = 0; k0 < D_MODELC; k0 += 32) {
        load_lds16(Ag + k0,              AsB);
        load_lds16(Ag + k0 + 16 * 1024,  AsB + 512);
        load_lds16(Bg + k0,              BsB);
        load_lds16(Bg + k0 + 16 * 1024,  BsB + 512);
        __syncthreads();
        short8 af[4], bfr[4];
        #pragma unroll
        for (int m = 0; m < 4; ++m)
            af[m] = *(const short8*)&As[wr * 64 + m * 16 + row16][(g8 ^ xc2) * 8];
        #pragma unroll
        for (int nn = 0; nn < 4; ++nn)
            bfr[nn] = *(const short8*)&Bs[wc * 64 + nn * 16 + row16][(g8 ^ xc2) * 8];
        #pragma unroll
        for (int m = 0; m < 4; ++m)
            #pragma unroll
            for (int nn = 0; nn < 4; ++nn)
                acc[m][nn] = MFMA16(af[m], bfr[nn], acc[m][nn]);
        __syncthreads();
    }

    float bvv[4], w1[4], w2[4];
    #pragma unroll
    for (int nn = 0; nn < 4; ++nn) {
        int c = col0 + wc * 64 + nn * 16 + row16;
        bvv[nn] = bias[c];
        w1[nn] = rwb[c];
        w2[nn] = rrb[c];
    }
    if (mode == 2) {
        #pragma unroll
        for (int m = 0; m < 4; ++m)
            #pragma unroll
            for (int nn = 0; nn < 4; ++nn) {
                int c = col0 + wc * 64 + nn * 16 + row16;
                #pragma unroll
                for (int reg = 0; reg < 4; ++reg) {
                    int r = row0 + wr * 64 + m * 16 + g8 * 4 + reg;
                    float v = acc[m][nn][reg] + bvv[nn];
                    // fold SCALE*log2(e) into q-side operands for attn
                    qw[(size_t)r * D_MODELC + c] = (short)f2bf((v + w1[nn]) * SL2C);
                    qr[(size_t)r * D_MODELC + c] = (short)f2bf((v + w2[nn]) * SL2C);
                }
            }
    } else {
        short* C = (mode == 0) ? kb : (mode == 1) ? vb : rk;
        #pragma unroll
        for (int m = 0; m < 4; ++m)
            #pragma unroll
            for (int nn = 0; nn < 4; ++nn) {
                int c = col0 + wc * 64 + nn * 16 + row16;
                #pragma unroll
                for (int reg = 0; reg < 4; ++reg) {
                    int r = row0 + wr * 64 + m * 16 + g8 * 4 + reg;
                    C[(size_t)r * D_MODELC + c] = (short)f2bf(acc[m][nn][reg] + bvv[nn]);
                }
            }
    }
}

// ---------------------------------------------------------------------------
// Wo GEMM, split-K=2: bf16 partials (summed + bias in LN). Round-8 loop.
// ---------------------------------------------------------------------------
__global__ __launch_bounds__(256, 3) void wo_gemm_kernel(
    const short* __restrict__ A, const short* __restrict__ Bt,
    short* __restrict__ out0, short* __restrict__ out1)
{
    __shared__ short As[128][32];
    __shared__ short Bs[128][32];
    const int kz = blockIdx.z;
    short* C = kz ? out1 : out0;
    const int row0 = blockIdx.y * 128, col0 = blockIdx.x * 128;
    const int t = threadIdx.x;
    const int lane = t & 63, wid = t >> 6;
    const int row16 = lane & 15, g8 = lane >> 4;
    const int wr = wid >> 1, wc = wid & 1;

    f32x4 acc[4][4];
    #pragma unroll
    for (int m = 0; m < 4; ++m)
        #pragma unroll
        for (int nn = 0; nn < 4; ++nn)
            acc[m][nn] = (f32x4){0.f, 0.f, 0.f, 0.f};

    short* AsB = &As[0][0] + wid * 1024;
    short* BsB = &Bs[0][0] + wid * 1024;
    const int srow4 = lane >> 2;
    const int cs4 = (lane & 3) ^ ((lane >> 3) & 3);
    const short* Ag = A  + (size_t)(row0 + wid * 32 + srow4) * D_MODELC + cs4 * 8;
    const short* Bg = Bt + (size_t)(col0 + wid * 32 + srow4) * D_MODELC + cs4 * 8;
    const int xc2 = (row16 >> 1) & 3;

    const int kbase = kz * 512;
    for (int k0 = kbase; k0 < kbase + 512; k0 += 32) {
        load_lds16(Ag + k0,             AsB);
        load_lds16(Ag + k0 + 16 * 1024, AsB + 512);
        load_lds16(Bg + k0,             BsB);
        load_lds16(Bg + k0 + 16 * 1024, BsB + 512);
        __syncthreads();
        short8 af[4], bfr[4];
        #pragma unroll
        for (int m = 0; m < 4; ++m)
            af[m] = *(const short8*)&As[wr * 64 + m * 16 + row16][(g8 ^ xc2) * 8];
        #pragma unroll
        for (int nn = 0; nn < 4; ++nn)
            bfr[nn] = *(const short8*)&Bs[wc * 64 + nn * 16 + row16][(g8 ^ xc2) * 8];
        #pragma unroll
        for (int m = 0; m < 4; ++m)
            #pragma unroll
            for (int nn = 0; nn < 4; ++nn)
                acc[m][nn] = MFMA16(af[m], bfr[nn], acc[m][nn]);
        __syncthreads();
    }

    #pragma unroll
    for (int m = 0; m < 4; ++m)
        #pragma unroll
        for (int nn = 0; nn < 4; ++nn) {
            int c = col0 + wc * 64 + nn * 16 + row16;
            #pragma unroll
            for (int reg = 0; reg < 4; ++reg) {
                int r = row0 + wr * 64 + m * 16 + g8 * 4 + reg;
                C[(size_t)r * D_MODELC + c] = (short)f2bf(acc[m][nn][reg]);
            }
        }
}

// ---------------------------------------------------------------------------
// LDS-staged MFMA flash attention, S^T softmax (round-13 structure) with:
//  - staging + end barrier SKIPPED on the final step (block-uniform guard)
//  - #pragma unroll 2 + cur = s&1 for static buffer addressing
// ---------------------------------------------------------------------------
__global__ __launch_bounds__(256, 2) void attn_mfma_kernel(
    const short* __restrict__ qw, const short* __restrict__ qr,
    const short* __restrict__ kb, const short* __restrict__ rkb,
    const short* __restrict__ vt, short* __restrict__ av)
{
    __shared__ short Kl[2][64][64];      // 16 KB (dbuf)
    __shared__ short Vl[2][64][64];      // 16 KB (dbuf, [d][j])
    __shared__ short Rl[RINGC][64];      // 24 KB (rk ring, row = jr % 192)
    __shared__ short pun[4][1376];       // 11 KB: bdT [16][84] alias P [16][64]
    __shared__ float scb[4][16];         // sc / lsum broadcast

    const int wave = threadIdx.x >> 6, lane = threadIdx.x & 63;
    const int row16 = lane & 15, g8 = lane >> 4;
    const int srow = lane >> 3, chk = lane & 7;
    const int swz = srow & 7;            // staging source-chunk xor

    // balanced + XCD-contiguous remap: CU gets ic and 15-ic (pair sum uniform)
    const int lin = blockIdx.y * 16 + blockIdx.x;   // 0..511
    const int xcd = lin & 7;
    const int u   = lin >> 3;                        // 0..63
    const int v   = u & 31;
    const int bn  = xcd * 4 + (v >> 3);
    const int tt  = v & 7;
    const int ic  = (u >> 5) ? (15 - tt) : tt;
    const int b = bn & 1, n = bn >> 1;
    const int i0 = ic * 64;
    const int i0w = i0 + wave * 16;

    // Q fragments (row = i0w+row16, k = ks*32 + g8*8 + e), pre-scaled by SL2C
    short8 qwf[2], qrf[2];
    #pragma unroll
    for (int ks = 0; ks < 2; ++ks) {
        size_t off = ((size_t)(i0w + row16) * 2 + b) * D_MODELC + n * 64 + ks * 32 + g8 * 8;
        qwf[ks] = *(const short8*)(qw + off);
        qrf[ks] = *(const short8*)(qr + off);
    }

    // ---- prologue: stage K(0), V(0), rk window(0) = [960-i0, 1088-i0) ----
    #pragma unroll
    for (int t = 0; t < 2; ++t) {
        int rr = wave * 16 + t * 8;
        int j  = rr + srow;
        int cs = chk ^ swz;
        load_lds16(kb + ((size_t)j * 2 + b) * D_MODELC + n * 64 + cs * 8, &Kl[0][rr][0]);
        load_lds16(vt + ((size_t)((b * 16 + n) * 64 + rr + srow)) * KLENC + cs * 8,
                   &Vl[0][rr][0]);
    }
    {
        const int p0 = 960 - i0;                  // multiple of 8 (>=0)
        #pragma unroll
        for (int t = 0; t < 4; ++t) {
            int jrb_ = p0 + wave * 32 + t * 8;
            int slotb = jrb_ % RINGC;
            int jr = jrb_ + srow;
            int jc = jr < KLENC ? jr : KLENC - 1;
            int cs = chk ^ swz;
            load_lds16(rkb + (size_t)jc * D_MODELC + n * 64 + cs * 8, &Rl[slotb][0]);
        }
    }

    f32x4 accO[4];
    #pragma unroll
    for (int dt = 0; dt < 4; ++dt) accO[dt] = (f32x4){0.f, 0.f, 0.f, 0.f};
    float m = -INFINITY;                 // row-uniform running max (log2 domain)
    float lsum = 0.f;                    // PER-LANE partial sum (reduced at end)

    const int T = (i0 + 63 + MEMLENC + 64) >> 6;
    const int r7 = row16 & 7;

    __syncthreads();

    #pragma unroll 2
    for (int s = 0; s < T; ++s) {
        const int j0 = s * 64;
        const int cur = s & 1;
        const int nxt = cur ^ 1;
        const bool stage = (s + 1 < T);   // block-uniform

        // ---------- issue async staging for step s+1 (skipped on last step) ----------
        if (stage) {
            #pragma unroll
            for (int t = 0; t < 2; ++t) {             // K(s+1)
                int rr = wave * 16 + t * 8;
                int j  = j0 + 64 + rr + srow;
                if (j > KLENC - 1) j = KLENC - 1;
                int cs = chk ^ swz;
                load_lds16(kb + ((size_t)j * 2 + b) * D_MODELC + n * 64 + cs * 8, &Kl[nxt][rr][0]);
            }
            {
                const int nb = j0 + 1088 - i0;        // new rk rows for window(s+1)
                #pragma unroll
                for (int t = 0; t < 2; ++t) {
                    int jrb_ = nb + wave * 16 + t * 8;
                    int slotb = jrb_ % RINGC;
                    int jr = jrb_ + srow;
                    int jc = jr < KLENC ? jr : KLENC - 1;
                    int cs = chk ^ swz;
                    load_lds16(rkb + (size_t)jc * D_MODELC + n * 64 + cs * 8, &Rl[slotb][0]);
                }
            }
            {
                const int jsrc = (j0 + 64 <= KLENC - 64) ? (j0 + 64) : (KLENC - 64);
                #pragma unroll
                for (int t = 0; t < 2; ++t) {         // V(s+1), d-major
                    int rr = wave * 16 + t * 8;
                    int cs = chk ^ swz;
                    load_lds16(vt + ((size_t)((b * 16 + n) * 64 + rr + srow)) * KLENC + jsrc + cs * 8,
                               &Vl[nxt][rr][0]);
                }
            }
        }

        // ---------- AC^T = MFMA(K, Qw): lane holds j=g8*4+reg(+jt*16), i=row16 ----------
        __builtin_amdgcn_s_setprio(1);
        f32x4 st[4];
        #pragma unroll
        for (int jt = 0; jt < 4; ++jt) {
            st[jt] = (f32x4){0.f, 0.f, 0.f, 0.f};
            const short* kr = &Kl[cur][jt * 16 + row16][0];
            st[jt] = MFMA16(*(const short8*)(kr + ((g8 ^ r7) * 8)),       qwf[0], st[jt]);
            st[jt] = MFMA16(*(const short8*)(kr + (((4 + g8) ^ r7) * 8)), qwf[1], st[jt]);
        }

        // ---------- BD^T over jr window from ring; bdT[i][jr_loc] packed b64 ----------
        const int jrb_w = j0 - i0w + 1008;
        const int sb = jrb_w % RINGC;
        short* bdT = &pun[wave][0];               // [16][84]
        #pragma unroll
        for (int rt = 0; rt < 5; ++rt) {
            int rsl = sb + rt * 16 + row16;
            if (rsl >= RINGC) rsl -= RINGC;
            const short* rr = &Rl[rsl][0];
            f32x4 bd = (f32x4){0.f, 0.f, 0.f, 0.f};
            bd = MFMA16(*(const short8*)(rr + ((g8 ^ r7) * 8)),       qrf[0], bd);
            bd = MFMA16(*(const short8*)(rr + (((4 + g8) ^ r7) * 8)), qrf[1], bd);
            uint2 wv;
            wv.x = pk2(bd[0], bd[1]);
            wv.y = pk2(bd[2], bd[3]);
            *(uint2*)&bdT[row16 * 84 + rt * 16 + g8 * 4] = wv;
        }
        __builtin_amdgcn_s_setprio(0);

        // ---------- combine (+mask only on tail steps; scale pre-folded) ----------
        float sl[4][4];
        if (j0 + 63 <= i0w + MEMLENC) {
            #pragma unroll
            for (int jt = 0; jt < 4; ++jt)
                #pragma unroll
                for (int reg = 0; reg < 4; ++reg) {
                    const int jl = jt * 16 + g8 * 4 + reg;
                    sl[jt][reg] = st[jt][reg] + bf2f(bdT[row16 * 84 + jl + 15 - row16]);
                }
        } else {
            #pragma unroll
            for (int jt = 0; jt < 4; ++jt)
                #pragma unroll
                for (int reg = 0; reg < 4; ++reg) {
                    const int jl = jt * 16 + g8 * 4 + reg;
                    float vv = st[jt][reg] + bf2f(bdT[row16 * 84 + jl + 15 - row16]);
                    sl[jt][reg] = (j0 + jl > i0w + row16 + MEMLENC) ? -INFINITY : vv;
                }
        }

        // ---------- in-lane max tree (no cross-lane shuffles on fast path) ----------
        float mx0 = fmaxf(fmaxf(sl[0][0], sl[0][1]), fmaxf(sl[0][2], sl[0][3]));
        float mx1 = fmaxf(fmaxf(sl[1][0], sl[1][1]), fmaxf(sl[1][2], sl[1][3]));
        float mx2 = fmaxf(fmaxf(sl[2][0], sl[2][1]), fmaxf(sl[2][2], sl[2][3]));
        float mx3 = fmaxf(fmaxf(sl[3][0], sl[3][1]), fmaxf(sl[3][2], sl[3][3]));
        float mx = fmaxf(fmaxf(mx0, mx1), fmaxf(mx2, mx3));

        // ---------- defer-max rescale (rare; row-max shuffles only here) ----------
        if (__any(mx > m + 8.f)) {
            float mxr = mx;
            mxr = fmaxf(mxr, __shfl_xor(mxr, 16, 64));
            mxr = fmaxf(mxr, __shfl_xor(mxr, 32, 64));   // row max (row-uniform)
            float mn = fmaxf(m, mxr);
            float sc = exp2f(m - mn);            // first step: exp2(-inf)=0
            m = mn;
            lsum *= sc;
            if (lane < 16) scb[wave][lane] = sc;
            float4 s4 = *(const float4*)&scb[wave][g8 * 4];
            #pragma unroll
            for (int dt = 0; dt < 4; ++dt) {
                accO[dt][0] *= s4.x; accO[dt][1] *= s4.y;
                accO[dt][2] *= s4.z; accO[dt][3] *= s4.w;
            }
        }

        // ---------- P = exp2(S - m), packed b64 store, per-lane partial sum ----------
        #pragma unroll
        for (int jt = 0; jt < 4; ++jt)
            #pragma unroll
            for (int reg = 0; reg < 4; ++reg)
                sl[jt][reg] = exp2f(sl[jt][reg] - m);
        float ps = ((sl[0][0] + sl[0][1]) + (sl[0][2] + sl[0][3]))
                 + ((sl[1][0] + sl[1][1]) + (sl[1][2] + sl[1][3]))
                 + ((sl[2][0] + sl[2][1]) + (sl[2][2] + sl[2][3]))
                 + ((sl[3][0] + sl[3][1]) + (sl[3][2] + sl[3][3]));
        short* pP = &pun[wave][0];               // overwrites bdT (reads done, same wave)
        #pragma unroll
        for (int jt = 0; jt < 4; ++jt) {
            const int ch = (jt * 2 + (g8 >> 1)) ^ r7;
            uint2 pkd;
            pkd.x = pk2(sl[jt][0], sl[jt][1]);
            pkd.y = pk2(sl[jt][2], sl[jt][3]);
            *(uint2*)&pP[row16 * 64 + ch * 8 + (g8 & 1) * 4] = pkd;
        }
        lsum += ps;                              // per-lane partial; no shuffles

        // ---------- PV: O += P @ V from Vl[cur] ----------
        __builtin_amdgcn_s_setprio(1);
        #pragma unroll
        for (int ks2 = 0; ks2 < 2; ++ks2) {
            short8 pf = *(const short8*)&pP[row16 * 64 + (((ks2 * 4 + g8) ^ r7) * 8)];
            #pragma unroll
            for (int dt = 0; dt < 4; ++dt) {
                const short* vp = &Vl[cur][dt * 16 + row16][(((ks2 * 4 + g8) ^ r7) * 8)];
                accO[dt] = MFMA16(pf, *(const short8*)vp, accO[dt]);
            }
        }
        __builtin_amdgcn_s_setprio(0);

        if (stage) __syncthreads();   // drains staging; skipped on final step
    }

    // ---- epilogue: reduce per-lane lsum across the row's 4 lanes, store ----
    lsum += __shfl_xor(lsum, 16, 64);
    lsum += __shfl_xor(lsum, 32, 64);
    if (lane < 16) scb[wave][lane] = lsum;
    float4 l4 = *(const float4*)&scb[wave][g8 * 4];
    float rl4[4] = {1.f / l4.x, 1.f / l4.y, 1.f / l4.z, 1.f / l4.w};
    #pragma unroll
    for (int dt = 0; dt < 4; ++dt)
        #pragma unroll
        for (int reg = 0; reg < 4; ++reg) {
            size_t o = ((size_t)(i0w + g8 * 4 + reg) * 2 + b) * D_MODELC + n * 64 + dt * 16 + row16;
            av[o] = (short)f2bf(accO[dt][reg] * rl4[reg]);
        }
}

// ---------------------------------------------------------------------------
// Residual + bias + LayerNorm: x = w + bf(p0) + bf(p1) + bo
// ---------------------------------------------------------------------------
__global__ __launch_bounds__(256) void ln_kernel(
    const float* __restrict__ w, const short* __restrict__ p0,
    const short* __restrict__ p1, const float* __restrict__ bo,
    const float* __restrict__ g, const float* __restrict__ bb,
    float* __restrict__ out)
{
    __shared__ float red[2][4];
    const int row = blockIdx.x;
    const int lane = threadIdx.x & 63;
    const int wv = threadIdx.x >> 6;
    const size_t base = (size_t)row * D_MODELC;
    const int c = threadIdx.x * 4;

    float4 xw = *(const float4*)&w[base + c];
    ushort4 a0 = *(const ushort4*)&p0[base + c];
    ushort4 a1 = *(const ushort4*)&p1[base + c];
    float4 xb = *(const float4*)&bo[c];
    float x[4] = {xw.x + bf2f((short)a0.x) + bf2f((short)a1.x) + xb.x,
                  xw.y + bf2f((short)a0.y) + bf2f((short)a1.y) + xb.y,
                  xw.z + bf2f((short)a0.z) + bf2f((short)a1.z) + xb.z,
                  xw.w + bf2f((short)a0.w) + bf2f((short)a1.w) + xb.w};

    float sum = x[0] + x[1] + x[2] + x[3];
    float ssq = x[0]*x[0] + x[1]*x[1] + x[2]*x[2] + x[3]*x[3];
    #pragma unroll
    for (int off = 32; off > 0; off >>= 1) {
        sum += __shfl_xor(sum, off, 64);
        ssq += __shfl_xor(ssq, off, 64);
    }
    if (lane == 0) { red[0][wv] = sum; red[1][wv] = ssq; }
    __syncthreads();
    sum = red[0][0] + red[0][1] + red[0][2] + red[0][3];
    ssq = red[1][0] + red[1][1] + red[1][2] + red[1][3];

    const float mu = sum * (1.0f / D_MODELC);
    const float var = ssq * (1.0f / D_MODELC) - mu * mu;
    const float rstd = rsqrtf(var + LN_EPSC);

    float4 o;
    o.x = (x[0] - mu) * rstd * g[c] + bb[c];
    o.y = (x[1] - mu) * rstd * g[c+1] + bb[c+1];
    o.z = (x[2] - mu) * rstd * g[c+2] + bb[c+2];
    o.w = (x[3] - mu) * rstd * g[c+3] + bb[c+3];
    *(float4*)&out[base + c] = o;
}

// ---------------------------------------------------------------------------
extern "C" void kernel_launch(void* const* d_in, const int* in_sizes, int n_in,
                              void* d_out, int out_size, void* d_ws, size_t ws_size,
                              hipStream_t stream)
{
    const float* w    = (const float*)d_in[0];
    const float* r    = (const float*)d_in[1];
    const float* mems = (const float*)d_in[2];
    const float* rwb  = (const float*)d_in[3];
    const float* rrb  = (const float*)d_in[4];
    // d_in[5] = attn_mask — deterministic causal+mem pattern, handled analytically
    const float* Wq = (const float*)d_in[6];
    const float* bq = (const float*)d_in[7];
    const float* Wk = (const float*)d_in[8];
    const float* bk = (const float*)d_in[9];
    const float* Wv = (const float*)d_in[10];
    const float* bv = (const float*)d_in[11];
    const float* Wr = (const float*)d_in[12];
    const float* br = (const float*)d_in[13];
    const float* Wo = (const float*)d_in[14];
    const float* bo = (const float*)d_in[15];
    const float* ln_g = (const float*)d_in[16];
    const float* ln_b = (const float*)d_in[17];
    float* out = (float*)d_out;

    char* ws = (char*)d_ws;
    const size_t MB = 1ull << 20;
    short* cat_bf = (short*)(ws + 0 * MB);    // 8 MB
    short* r_bf   = (short*)(ws + 8 * MB);    // 4 MB
    short* Wq_t   = (short*)(ws + 12 * MB);   // dead after proj -> wo out0
    short* Wk_t   = (short*)(ws + 14 * MB);
    short* Wv_t   = (short*)(ws + 16 * MB);   // dead after proj -> wo out1
    short* Wr_t   = (short*)(ws + 18 * MB);
    short* Wo_t   = (short*)(ws + 20 * MB);   // needed until wo_gemm
    short* qw_bf  = (short*)(ws + 22 * MB);
    short* qr_bf  = (short*)(ws + 26 * MB);
    short* k_bf   = (short*)(ws + 30 * MB);   // 8 MB
    short* v_bf   = (short*)(ws + 38 * MB);   // 8 MB
    short* rk_bf  = (short*)(ws + 46 * MB);
    short* vt     = (short*)(ws + 50 * MB);   // 8 MB
    short* av_bf  = (short*)(ws + 58 * MB);
    short* wo0    = Wq_t;                     // 4 MB (12..16)
    short* wo1    = Wv_t;                     // 4 MB (16..20)

    dim3 blk(256);

    // fused casts + weight transposes
    prep_kernel<<<dim3(16, 16, 17), blk, 0, stream>>>(
        mems, w, r, Wq, Wk, Wv, Wr, Wo,
        cat_bf, r_bf, Wq_t, Wk_t, Wv_t, Wr_t, Wo_t);

    // fused projections (K, V, Q->qw/qr scaled, RK)
    proj_gemm_kernel<<<dim3(8, 96), blk, 0, stream>>>(
        cat_bf, r_bf, Wq_t, Wk_t, Wv_t, Wr_t,
        bq, bk, bv, br, rwb, rrb,
        qw_bf, qr_bf, k_bf, v_bf, rk_bf);

    // V transpose
    vtrans_kernel<<<dim3(32, 32), blk, 0, stream>>>(v_bf, vt);

    // attention (round-13 structure + last-step destaging + unroll 2): grid 512
    attn_mfma_kernel<<<dim3(16, 32), blk, 0, stream>>>(
        qw_bf, qr_bf, k_bf, rk_bf, vt, av_bf);

    // output projection split-K (bf16 partials; summed + bias in LN)
    wo_gemm_kernel<<<dim3(8, 16, 2), blk, 0, stream>>>(av_bf, Wo_t, wo0, wo1);

    // LN(w + wo0 + wo1 + bo)
    ln_kernel<<<dim3(2048), blk, 0, stream>>>(w, wo0, wo1, bo, ln_g, ln_b, out);
}

// Round 15
// 138.413 us; speedup vs baseline: 1.2660x; 1.0775x over previous
//
#include <hip/hip_runtime.h>
#include <math.h>

#define N_HEADC 16
#define D_MODELC 1024
#define D_HEADC 64
#define QLENC 1024
#define BSZC 2
#define MEMLENC 1024
#define KLENC 2048
#define SCALEC 0.125f
#define SL2C 0.18033688011112042f   // SCALE * log2(e)
#define LN_EPSC 1e-5f
#define RINGC 192

typedef __attribute__((ext_vector_type(8))) short short8;
typedef __attribute__((ext_vector_type(4))) float f32x4;

#define MFMA16(a, b, c) __builtin_amdgcn_mfma_f32_16x16x32_bf16((a), (b), (c), 0, 0, 0)

__device__ inline unsigned short f2bf(float x) {
    union { float f; unsigned int u; } c; c.f = x;
    unsigned int r = c.u + 0x7FFFu + ((c.u >> 16) & 1u);
    return (unsigned short)(r >> 16);
}
__device__ inline unsigned int pk2(float a, float b) { // 2xbf16 trunc pack
    union { float f; unsigned int u; } x, y; x.f = a; y.f = b;
    return (x.u >> 16) | (y.u & 0xFFFF0000u);
}
__device__ inline float bf2f(short s) {
    union { unsigned int u; float f; } c; c.u = ((unsigned int)(unsigned short)s) << 16;
    return c.f;
}
__device__ inline float asf(unsigned u) {
    union { unsigned int u; float f; } c; c.u = u; return c.f;
}

// async global->LDS, 16B per lane; lds dest = wave-uniform base + lane*16
__device__ __forceinline__ void load_lds16(const short* g, short* l) {
    __builtin_amdgcn_global_load_lds(
        (const __attribute__((address_space(1))) void*)g,
        (__attribute__((address_space(3))) void*)l,
        16, 0, 0);
}

// ---------------------------------------------------------------------------
// Fused prep: z<5 -> transpose+cast W_z; z>=5 -> flat bf16 casts (cat, r)
// grid (16,16,17)
// ---------------------------------------------------------------------------
__global__ __launch_bounds__(256) void prep_kernel(
    const float* __restrict__ mems, const float* __restrict__ wIn,
    const float* __restrict__ rIn,
    const float* __restrict__ W0, const float* __restrict__ W1,
    const float* __restrict__ W2, const float* __restrict__ W3,
    const float* __restrict__ W4,
    short* __restrict__ cat_bf, short* __restrict__ r_bf,
    short* __restrict__ D0, short* __restrict__ D1, short* __restrict__ D2,
    short* __restrict__ D3, short* __restrict__ D4)
{
    __shared__ short tile[64][72];
    const int z = blockIdx.z;
    const int t = threadIdx.x;

    if (z >= 5) {
        int lb = (z - 5) * 256 + blockIdx.y * 16 + blockIdx.x;
        int idx = (lb * 256 + t) * 8;
        const float* src; short* dst;
        if (idx < 4194304) {            // cat = [mems(2M); w(2M)]
            src = (idx < 2097152) ? (mems + idx) : (wIn + idx - 2097152);
            dst = cat_bf + idx;
        } else {
            src = rIn + (idx - 4194304);
            dst = r_bf + (idx - 4194304);
        }
        short8 o;
        #pragma unroll
        for (int e = 0; e < 8; ++e) o[e] = (short)f2bf(src[e]);
        *(short8*)dst = o;
        return;
    }

    const float* W; short* D;
    switch (z) {
        case 0: W = W0; D = D0; break;
        case 1: W = W1; D = D1; break;
        case 2: W = W2; D = D2; break;
        case 3: W = W3; D = D3; break;
        default: W = W4; D = D4; break;
    }
    const int n0 = blockIdx.x * 64, k0 = blockIdx.y * 64;
    #pragma unroll
    for (int it = 0; it < 2; ++it) {
        int idx = t + it * 256;
        int kl = idx >> 3, c8 = idx & 7;
        const float* src = W + (size_t)(k0 + kl) * D_MODELC + n0 + c8 * 8;
        short8 s;
        #pragma unroll
        for (int e = 0; e < 8; ++e) s[e] = (short)f2bf(src[e]);
        *(short8*)&tile[kl][c8 * 8] = s;
    }
    __syncthreads();
    #pragma unroll
    for (int it = 0; it < 2; ++it) {
        int idx = t + it * 256;
        int nl = idx >> 3, c8 = idx & 7;
        short8 s;
        #pragma unroll
        for (int e = 0; e < 8; ++e) s[e] = tile[c8 * 8 + e][nl];
        *(short8*)(D + (size_t)(n0 + nl) * D_MODELC + k0 + c8 * 8) = s;
    }
}

// ---------------------------------------------------------------------------
// V transpose: v_bf [4096][1024] (row=j*2+b, col=n*64+d) -> vt [b][n][d=64][j=2048]
// ---------------------------------------------------------------------------
__global__ __launch_bounds__(256) void vtrans_kernel(
    const short* __restrict__ v_bf, short* __restrict__ vt)
{
    __shared__ short tile[64][72];
    const int t = threadIdx.x;
    const int j0 = blockIdx.x * 64;
    const int bn = blockIdx.y;
    const int b = bn & 1, n = bn >> 1;
    #pragma unroll
    for (int it = 0; it < 2; ++it) {
        int idx = t + it * 256;
        int jl = idx >> 3, c8 = idx & 7;
        short8 s = *(const short8*)(v_bf + ((size_t)(j0 + jl) * 2 + b) * D_MODELC + n * 64 + c8 * 8);
        *(short8*)&tile[jl][c8 * 8] = s;
    }
    __syncthreads();
    #pragma unroll
    for (int it = 0; it < 2; ++it) {
        int idx = t + it * 256;
        int dl = idx >> 3, c8 = idx & 7;
        short8 s;
        #pragma unroll
        for (int e = 0; e < 8; ++e) s[e] = tile[c8 * 8 + e][dl];
        *(short8*)(vt + ((size_t)(b * 16 + n) * 64 + dl) * (size_t)KLENC + j0 + c8 * 8) = s;
    }
}

// ---------------------------------------------------------------------------
// Fused projection GEMMs (K, V, Q, RK) via global_load_lds, 128x128 tile, BK=32.
// ---------------------------------------------------------------------------
__global__ __launch_bounds__(256, 3) void proj_gemm_kernel(
    const short* __restrict__ cat, const short* __restrict__ rin,
    const short* __restrict__ WqT, const short* __restrict__ WkT,
    const short* __restrict__ WvT, const short* __restrict__ WrT,
    const float* __restrict__ bq, const float* __restrict__ bk,
    const float* __restrict__ bv, const float* __restrict__ br,
    const float* __restrict__ rwb, const float* __restrict__ rrb,
    short* __restrict__ qw, short* __restrict__ qr,
    short* __restrict__ kb, short* __restrict__ vb, short* __restrict__ rk)
{
    __shared__ short As[128][32];
    __shared__ short Bs[128][32];

    const int lin = blockIdx.y * 8 + blockIdx.x;        // 0..767
    const int sw  = (lin & 7) * 96 + (lin >> 3);        // XCD-contiguous
    const int bx  = sw & 7;
    const int by  = sw >> 3;

    const short* A; const short* Bt; const float* bias; int yt, mode;
    if (by < 32)      { A = cat;                         Bt = WkT; bias = bk; yt = by;      mode = 0; }
    else if (by < 64) { A = cat;                         Bt = WvT; bias = bv; yt = by - 32; mode = 1; }
    else if (by < 80) { A = cat + (size_t)2048 * 1024;   Bt = WqT; bias = bq; yt = by - 64; mode = 2; }
    else              { A = rin;                         Bt = WrT; bias = br; yt = by - 80; mode = 3; }

    const int row0 = yt * 128, col0 = bx * 128;
    const int t = threadIdx.x;
    const int lane = t & 63, wid = t >> 6;
    const int row16 = lane & 15, g8 = lane >> 4;
    const int wr = wid >> 1, wc = wid & 1;

    f32x4 acc[4][4];
    #pragma unroll
    for (int m = 0; m < 4; ++m)
        #pragma unroll
        for (int nn = 0; nn < 4; ++nn)
            acc[m][nn] = (f32x4){0.f, 0.f, 0.f, 0.f};

    short* AsB = &As[0][0] + wid * 1024;
    short* BsB = &Bs[0][0] + wid * 1024;
    const int srow4 = lane >> 2;
    const int cs4 = (lane & 3) ^ ((lane >> 3) & 3);     // swizzled source chunk
    const short* Ag = A  + (size_t)(row0 + wid * 32 + srow4) * D_MODELC + cs4 * 8;
    const short* Bg = Bt + (size_t)(col0 + wid * 32 + srow4) * D_MODELC + cs4 * 8;
    const int xc2 = (row16 >> 1) & 3;                   // read-side xor

    for (int k0 = 0; k0 < D_MODELC; k0 += 32) {
        load_lds16(Ag + k0,              AsB);
        load_lds16(Ag + k0 + 16 * 1024,  AsB + 512);
        load_lds16(Bg + k0,              BsB);
        load_lds16(Bg + k0 + 16 * 1024,  BsB + 512);
        __syncthreads();
        short8 af[4], bfr[4];
        #pragma unroll
        for (int m = 0; m < 4; ++m)
            af[m] = *(const short8*)&As[wr * 64 + m * 16 + row16][(g8 ^ xc2) * 8];
        #pragma unroll
        for (int nn = 0; nn < 4; ++nn)
            bfr[nn] = *(const short8*)&Bs[wc * 64 + nn * 16 + row16][(g8 ^ xc2) * 8];
        #pragma unroll
        for (int m = 0; m < 4; ++m)
            #pragma unroll
            for (int nn = 0; nn < 4; ++nn)
                acc[m][nn] = MFMA16(af[m], bfr[nn], acc[m][nn]);
        __syncthreads();
    }

    float bvv[4], w1[4], w2[4];
    #pragma unroll
    for (int nn = 0; nn < 4; ++nn) {
        int c = col0 + wc * 64 + nn * 16 + row16;
        bvv[nn] = bias[c];
        w1[nn] = rwb[c];
        w2[nn] = rrb[c];
    }
    if (mode == 2) {
        #pragma unroll
        for (int m = 0; m < 4; ++m)
            #pragma unroll
            for (int nn = 0; nn < 4; ++nn) {
                int c = col0 + wc * 64 + nn * 16 + row16;
                #pragma unroll
                for (int reg = 0; reg < 4; ++reg) {
                    int r = row0 + wr * 64 + m * 16 + g8 * 4 + reg;
                    float v = acc[m][nn][reg] + bvv[nn];
                    // fold SCALE*log2(e) into q-side operands for attn
                    qw[(size_t)r * D_MODELC + c] = (short)f2bf((v + w1[nn]) * SL2C);
                    qr[(size_t)r * D_MODELC + c] = (short)f2bf((v + w2[nn]) * SL2C);
                }
            }
    } else {
        short* C = (mode == 0) ? kb : (mode == 1) ? vb : rk;
        #pragma unroll
        for (int m = 0; m < 4; ++m)
            #pragma unroll
            for (int nn = 0; nn < 4; ++nn) {
                int c = col0 + wc * 64 + nn * 16 + row16;
                #pragma unroll
                for (int reg = 0; reg < 4; ++reg) {
                    int r = row0 + wr * 64 + m * 16 + g8 * 4 + reg;
                    C[(size_t)r * D_MODELC + c] = (short)f2bf(acc[m][nn][reg] + bvv[nn]);
                }
            }
    }
}

// ---------------------------------------------------------------------------
// Wo GEMM, split-K=2: bf16 partials (summed + bias in LN). Round-8 loop.
// ---------------------------------------------------------------------------
__global__ __launch_bounds__(256, 3) void wo_gemm_kernel(
    const short* __restrict__ A, const short* __restrict__ Bt,
    short* __restrict__ out0, short* __restrict__ out1)
{
    __shared__ short As[128][32];
    __shared__ short Bs[128][32];
    const int kz = blockIdx.z;
    short* C = kz ? out1 : out0;
    const int row0 = blockIdx.y * 128, col0 = blockIdx.x * 128;
    const int t = threadIdx.x;
    const int lane = t & 63, wid = t >> 6;
    const int row16 = lane & 15, g8 = lane >> 4;
    const int wr = wid >> 1, wc = wid & 1;

    f32x4 acc[4][4];
    #pragma unroll
    for (int m = 0; m < 4; ++m)
        #pragma unroll
        for (int nn = 0; nn < 4; ++nn)
            acc[m][nn] = (f32x4){0.f, 0.f, 0.f, 0.f};

    short* AsB = &As[0][0] + wid * 1024;
    short* BsB = &Bs[0][0] + wid * 1024;
    const int srow4 = lane >> 2;
    const int cs4 = (lane & 3) ^ ((lane >> 3) & 3);
    const short* Ag = A  + (size_t)(row0 + wid * 32 + srow4) * D_MODELC + cs4 * 8;
    const short* Bg = Bt + (size_t)(col0 + wid * 32 + srow4) * D_MODELC + cs4 * 8;
    const int xc2 = (row16 >> 1) & 3;

    const int kbase = kz * 512;
    for (int k0 = kbase; k0 < kbase + 512; k0 += 32) {
        load_lds16(Ag + k0,             AsB);
        load_lds16(Ag + k0 + 16 * 1024, AsB + 512);
        load_lds16(Bg + k0,             BsB);
        load_lds16(Bg + k0 + 16 * 1024, BsB + 512);
        __syncthreads();
        short8 af[4], bfr[4];
        #pragma unroll
        for (int m = 0; m < 4; ++m)
            af[m] = *(const short8*)&As[wr * 64 + m * 16 + row16][(g8 ^ xc2) * 8];
        #pragma unroll
        for (int nn = 0; nn < 4; ++nn)
            bfr[nn] = *(const short8*)&Bs[wc * 64 + nn * 16 + row16][(g8 ^ xc2) * 8];
        #pragma unroll
        for (int m = 0; m < 4; ++m)
            #pragma unroll
            for (int nn = 0; nn < 4; ++nn)
                acc[m][nn] = MFMA16(af[m], bfr[nn], acc[m][nn]);
        __syncthreads();
    }

    #pragma unroll
    for (int m = 0; m < 4; ++m)
        #pragma unroll
        for (int nn = 0; nn < 4; ++nn) {
            int c = col0 + wc * 64 + nn * 16 + row16;
            #pragma unroll
            for (int reg = 0; reg < 4; ++reg) {
                int r = row0 + wr * 64 + m * 16 + g8 * 4 + reg;
                C[(size_t)r * D_MODELC + c] = (short)f2bf(acc[m][nn][reg]);
            }
        }
}

// ---------------------------------------------------------------------------
// LDS-staged MFMA flash attention (round-14 structure) with WINDOWED bdT
// combine reads: 16x ds_read_u16 -> 2x b64 per jt + funnel-shift extract
// (in-window shift (15-row16)&3 is lane-constant).
// ---------------------------------------------------------------------------
__global__ __launch_bounds__(256, 2) void attn_mfma_kernel(
    const short* __restrict__ qw, const short* __restrict__ qr,
    const short* __restrict__ kb, const short* __restrict__ rkb,
    const short* __restrict__ vt, short* __restrict__ av)
{
    __shared__ short Kl[2][64][64];      // 16 KB (dbuf)
    __shared__ short Vl[2][64][64];      // 16 KB (dbuf, [d][j])
    __shared__ short Rl[RINGC][64];      // 24 KB (rk ring, row = jr % 192)
    __shared__ short pun[4][1376];       // 11 KB: bdT [16][84] alias P [16][64]
    __shared__ float scb[4][16];         // sc / lsum broadcast

    const int wave = threadIdx.x >> 6, lane = threadIdx.x & 63;
    const int row16 = lane & 15, g8 = lane >> 4;
    const int srow = lane >> 3, chk = lane & 7;
    const int swz = srow & 7;            // staging source-chunk xor

    // balanced + XCD-contiguous remap: CU gets ic and 15-ic (pair sum uniform)
    const int lin = blockIdx.y * 16 + blockIdx.x;   // 0..511
    const int xcd = lin & 7;
    const int u   = lin >> 3;                        // 0..63
    const int v   = u & 31;
    const int bn  = xcd * 4 + (v >> 3);
    const int tt  = v & 7;
    const int ic  = (u >> 5) ? (15 - tt) : tt;
    const int b = bn & 1, n = bn >> 1;
    const int i0 = ic * 64;
    const int i0w = i0 + wave * 16;

    // Q fragments (row = i0w+row16, k = ks*32 + g8*8 + e), pre-scaled by SL2C
    short8 qwf[2], qrf[2];
    #pragma unroll
    for (int ks = 0; ks < 2; ++ks) {
        size_t off = ((size_t)(i0w + row16) * 2 + b) * D_MODELC + n * 64 + ks * 32 + g8 * 8;
        qwf[ks] = *(const short8*)(qw + off);
        qrf[ks] = *(const short8*)(qr + off);
    }

    // ---- prologue: stage K(0), V(0), rk window(0) = [960-i0, 1088-i0) ----
    #pragma unroll
    for (int t = 0; t < 2; ++t) {
        int rr = wave * 16 + t * 8;
        int j  = rr + srow;
        int cs = chk ^ swz;
        load_lds16(kb + ((size_t)j * 2 + b) * D_MODELC + n * 64 + cs * 8, &Kl[0][rr][0]);
        load_lds16(vt + ((size_t)((b * 16 + n) * 64 + rr + srow)) * KLENC + cs * 8,
                   &Vl[0][rr][0]);
    }
    {
        const int p0 = 960 - i0;                  // multiple of 8 (>=0)
        #pragma unroll
        for (int t = 0; t < 4; ++t) {
            int jrb_ = p0 + wave * 32 + t * 8;
            int slotb = jrb_ % RINGC;
            int jr = jrb_ + srow;
            int jc = jr < KLENC ? jr : KLENC - 1;
            int cs = chk ^ swz;
            load_lds16(rkb + (size_t)jc * D_MODELC + n * 64 + cs * 8, &Rl[slotb][0]);
        }
    }

    f32x4 accO[4];
    #pragma unroll
    for (int dt = 0; dt < 4; ++dt) accO[dt] = (f32x4){0.f, 0.f, 0.f, 0.f};
    float m = -INFINITY;                 // row-uniform running max (log2 domain)
    float lsum = 0.f;                    // PER-LANE partial sum (reduced at end)

    const int T = (i0 + 63 + MEMLENC + 64) >> 6;
    const int r7 = row16 & 7;
    const int off15 = 15 - row16;        // 0..15
    const int kal = off15 & ~3;          // aligned window base offset (u16)
    const unsigned ksh = (unsigned)(off15 & 3) * 16;  // bit shift within window

    __syncthreads();

    #pragma unroll 2
    for (int s = 0; s < T; ++s) {
        const int j0 = s * 64;
        const int cur = s & 1;
        const int nxt = cur ^ 1;
        const bool stage = (s + 1 < T);   // block-uniform

        // ---------- issue async staging for step s+1 (skipped on last step) ----------
        if (stage) {
            #pragma unroll
            for (int t = 0; t < 2; ++t) {             // K(s+1)
                int rr = wave * 16 + t * 8;
                int j  = j0 + 64 + rr + srow;
                if (j > KLENC - 1) j = KLENC - 1;
                int cs = chk ^ swz;
                load_lds16(kb + ((size_t)j * 2 + b) * D_MODELC + n * 64 + cs * 8, &Kl[nxt][rr][0]);
            }
            {
                const int nb = j0 + 1088 - i0;        // new rk rows for window(s+1)
                #pragma unroll
                for (int t = 0; t < 2; ++t) {
                    int jrb_ = nb + wave * 16 + t * 8;
                    int slotb = jrb_ % RINGC;
                    int jr = jrb_ + srow;
                    int jc = jr < KLENC ? jr : KLENC - 1;
                    int cs = chk ^ swz;
                    load_lds16(rkb + (size_t)jc * D_MODELC + n * 64 + cs * 8, &Rl[slotb][0]);
                }
            }
            {
                const int jsrc = (j0 + 64 <= KLENC - 64) ? (j0 + 64) : (KLENC - 64);
                #pragma unroll
                for (int t = 0; t < 2; ++t) {         // V(s+1), d-major
                    int rr = wave * 16 + t * 8;
                    int cs = chk ^ swz;
                    load_lds16(vt + ((size_t)((b * 16 + n) * 64 + rr + srow)) * KLENC + jsrc + cs * 8,
                               &Vl[nxt][rr][0]);
                }
            }
        }

        // ---------- AC^T = MFMA(K, Qw): lane holds j=g8*4+reg(+jt*16), i=row16 ----------
        __builtin_amdgcn_s_setprio(1);
        f32x4 st[4];
        #pragma unroll
        for (int jt = 0; jt < 4; ++jt) {
            st[jt] = (f32x4){0.f, 0.f, 0.f, 0.f};
            const short* kr = &Kl[cur][jt * 16 + row16][0];
            st[jt] = MFMA16(*(const short8*)(kr + ((g8 ^ r7) * 8)),       qwf[0], st[jt]);
            st[jt] = MFMA16(*(const short8*)(kr + (((4 + g8) ^ r7) * 8)), qwf[1], st[jt]);
        }

        // ---------- BD^T over jr window from ring; bdT[i][jr_loc] packed b64 ----------
        const int jrb_w = j0 - i0w + 1008;
        const int sb = jrb_w % RINGC;
        short* bdT = &pun[wave][0];               // [16][84]
        #pragma unroll
        for (int rt = 0; rt < 5; ++rt) {
            int rsl = sb + rt * 16 + row16;
            if (rsl >= RINGC) rsl -= RINGC;
            const short* rr = &Rl[rsl][0];
            f32x4 bd = (f32x4){0.f, 0.f, 0.f, 0.f};
            bd = MFMA16(*(const short8*)(rr + ((g8 ^ r7) * 8)),       qrf[0], bd);
            bd = MFMA16(*(const short8*)(rr + (((4 + g8) ^ r7) * 8)), qrf[1], bd);
            uint2 wv;
            wv.x = pk2(bd[0], bd[1]);
            wv.y = pk2(bd[2], bd[3]);
            *(uint2*)&bdT[row16 * 84 + rt * 16 + g8 * 4] = wv;
        }
        __builtin_amdgcn_s_setprio(0);

        // ---------- combine via windowed b64 reads + funnel extract ----------
        float sl[4][4];
        {
            const bool tail = !(j0 + 63 <= i0w + MEMLENC);
            #pragma unroll
            for (int jt = 0; jt < 4; ++jt) {
                const unsigned* pwd = (const unsigned*)&bdT[row16 * 84 + jt * 16 + g8 * 4 + kal];
                uint2 wa = *(const uint2*)pwd;         // halves 0..3
                uint2 wb = *(const uint2*)(pwd + 2);   // halves 4..7
                unsigned s0 = (ksh < 32) ? wa.x : wa.y;
                unsigned s1 = (ksh < 32) ? wa.y : wb.x;
                unsigned s2 = (ksh < 32) ? wb.x : wb.y;
                unsigned sh2 = ksh & 31;
                unsigned lo = (unsigned)(((((unsigned long long)s1) << 32) | s0) >> sh2);
                unsigned hi = (unsigned)(((((unsigned long long)s2) << 32) | s1) >> sh2);
                float b0 = asf(lo << 16), b1 = asf(lo & 0xffff0000u);
                float b2 = asf(hi << 16), b3 = asf(hi & 0xffff0000u);
                sl[jt][0] = st[jt][0] + b0;
                sl[jt][1] = st[jt][1] + b1;
                sl[jt][2] = st[jt][2] + b2;
                sl[jt][3] = st[jt][3] + b3;
                if (tail) {
                    #pragma unroll
                    for (int reg = 0; reg < 4; ++reg) {
                        const int jl = jt * 16 + g8 * 4 + reg;
                        if (j0 + jl > i0w + row16 + MEMLENC) sl[jt][reg] = -INFINITY;
                    }
                }
            }
        }

        // ---------- in-lane max tree (no cross-lane shuffles on fast path) ----------
        float mx0 = fmaxf(fmaxf(sl[0][0], sl[0][1]), fmaxf(sl[0][2], sl[0][3]));
        float mx1 = fmaxf(fmaxf(sl[1][0], sl[1][1]), fmaxf(sl[1][2], sl[1][3]));
        float mx2 = fmaxf(fmaxf(sl[2][0], sl[2][1]), fmaxf(sl[2][2], sl[2][3]));
        float mx3 = fmaxf(fmaxf(sl[3][0], sl[3][1]), fmaxf(sl[3][2], sl[3][3]));
        float mx = fmaxf(fmaxf(mx0, mx1), fmaxf(mx2, mx3));

        // ---------- defer-max rescale (rare; row-max shuffles only here) ----------
        if (__any(mx > m + 8.f)) {
            float mxr = mx;
            mxr = fmaxf(mxr, __shfl_xor(mxr, 16, 64));
            mxr = fmaxf(mxr, __shfl_xor(mxr, 32, 64));   // row max (row-uniform)
            float mn = fmaxf(m, mxr);
            float sc = exp2f(m - mn);            // first step: exp2(-inf)=0
            m = mn;
            lsum *= sc;
            if (lane < 16) scb[wave][lane] = sc;
            float4 s4 = *(const float4*)&scb[wave][g8 * 4];
            #pragma unroll
            for (int dt = 0; dt < 4; ++dt) {
                accO[dt][0] *= s4.x; accO[dt][1] *= s4.y;
                accO[dt][2] *= s4.z; accO[dt][3] *= s4.w;
            }
        }

        // ---------- P = exp2(S - m), packed b64 store, per-lane partial sum ----------
        #pragma unroll
        for (int jt = 0; jt < 4; ++jt)
            #pragma unroll
            for (int reg = 0; reg < 4; ++reg)
                sl[jt][reg] = exp2f(sl[jt][reg] - m);
        float ps = ((sl[0][0] + sl[0][1]) + (sl[0][2] + sl[0][3]))
                 + ((sl[1][0] + sl[1][1]) + (sl[1][2] + sl[1][3]))
                 + ((sl[2][0] + sl[2][1]) + (sl[2][2] + sl[2][3]))
                 + ((sl[3][0] + sl[3][1]) + (sl[3][2] + sl[3][3]));
        short* pP = &pun[wave][0];               // overwrites bdT (reads done, same wave)
        #pragma unroll
        for (int jt = 0; jt < 4; ++jt) {
            const int ch = (jt * 2 + (g8 >> 1)) ^ r7;
            uint2 pkd;
            pkd.x = pk2(sl[jt][0], sl[jt][1]);
            pkd.y = pk2(sl[jt][2], sl[jt][3]);
            *(uint2*)&pP[row16 * 64 + ch * 8 + (g8 & 1) * 4] = pkd;
        }
        lsum += ps;                              // per-lane partial; no shuffles

        // ---------- PV: O += P @ V from Vl[cur] ----------
        __builtin_amdgcn_s_setprio(1);
        #pragma unroll
        for (int ks2 = 0; ks2 < 2; ++ks2) {
            short8 pf = *(const short8*)&pP[row16 * 64 + (((ks2 * 4 + g8) ^ r7) * 8)];
            #pragma unroll
            for (int dt = 0; dt < 4; ++dt) {
                const short* vp = &Vl[cur][dt * 16 + row16][(((ks2 * 4 + g8) ^ r7) * 8)];
                accO[dt] = MFMA16(pf, *(const short8*)vp, accO[dt]);
            }
        }
        __builtin_amdgcn_s_setprio(0);

        if (stage) __syncthreads();   // drains staging; skipped on final step
    }

    // ---- epilogue: reduce per-lane lsum across the row's 4 lanes, store ----
    lsum += __shfl_xor(lsum, 16, 64);
    lsum += __shfl_xor(lsum, 32, 64);
    if (lane < 16) scb[wave][lane] = lsum;
    float4 l4 = *(const float4*)&scb[wave][g8 * 4];
    float rl4[4] = {1.f / l4.x, 1.f / l4.y, 1.f / l4.z, 1.f / l4.w};
    #pragma unroll
    for (int dt = 0; dt < 4; ++dt)
        #pragma unroll
        for (int reg = 0; reg < 4; ++reg) {
            size_t o = ((size_t)(i0w + g8 * 4 + reg) * 2 + b) * D_MODELC + n * 64 + dt * 16 + row16;
            av[o] = (short)f2bf(accO[dt][reg] * rl4[reg]);
        }
}

// ---------------------------------------------------------------------------
// Residual + bias + LayerNorm: x = w + bf(p0) + bf(p1) + bo
// ---------------------------------------------------------------------------
__global__ __launch_bounds__(256) void ln_kernel(
    const float* __restrict__ w, const short* __restrict__ p0,
    const short* __restrict__ p1, const float* __restrict__ bo,
    const float* __restrict__ g, const float* __restrict__ bb,
    float* __restrict__ out)
{
    __shared__ float red[2][4];
    const int row = blockIdx.x;
    const int lane = threadIdx.x & 63;
    const int wv = threadIdx.x >> 6;
    const size_t base = (size_t)row * D_MODELC;
    const int c = threadIdx.x * 4;

    float4 xw = *(const float4*)&w[base + c];
    ushort4 a0 = *(const ushort4*)&p0[base + c];
    ushort4 a1 = *(const ushort4*)&p1[base + c];
    float4 xb = *(const float4*)&bo[c];
    float x[4] = {xw.x + bf2f((short)a0.x) + bf2f((short)a1.x) + xb.x,
                  xw.y + bf2f((short)a0.y) + bf2f((short)a1.y) + xb.y,
                  xw.z + bf2f((short)a0.z) + bf2f((short)a1.z) + xb.z,
                  xw.w + bf2f((short)a0.w) + bf2f((short)a1.w) + xb.w};

    float sum = x[0] + x[1] + x[2] + x[3];
    float ssq = x[0]*x[0] + x[1]*x[1] + x[2]*x[2] + x[3]*x[3];
    #pragma unroll
    for (int off = 32; off > 0; off >>= 1) {
        sum += __shfl_xor(sum, off, 64);
        ssq += __shfl_xor(ssq, off, 64);
    }
    if (lane == 0) { red[0][wv] = sum; red[1][wv] = ssq; }
    __syncthreads();
    sum = red[0][0] + red[0][1] + red[0][2] + red[0][3];
    ssq = red[1][0] + red[1][1] + red[1][2] + red[1][3];

    const float mu = sum * (1.0f / D_MODELC);
    const float var = ssq * (1.0f / D_MODELC) - mu * mu;
    const float rstd = rsqrtf(var + LN_EPSC);

    float4 o;
    o.x = (x[0] - mu) * rstd * g[c] + bb[c];
    o.y = (x[1] - mu) * rstd * g[c+1] + bb[c+1];
    o.z = (x[2] - mu) * rstd * g[c+2] + bb[c+2];
    o.w = (x[3] - mu) * rstd * g[c+3] + bb[c+3];
    *(float4*)&out[base + c] = o;
}

// ---------------------------------------------------------------------------
extern "C" void kernel_launch(void* const* d_in, const int* in_sizes, int n_in,
                              void* d_out, int out_size, void* d_ws, size_t ws_size,
                              hipStream_t stream)
{
    const float* w    = (const float*)d_in[0];
    const float* r    = (const float*)d_in[1];
    const float* mems = (const float*)d_in[2];
    const float* rwb  = (const float*)d_in[3];
    const float* rrb  = (const float*)d_in[4];
    // d_in[5] = attn_mask — deterministic causal+mem pattern, handled analytically
    const float* Wq = (const float*)d_in[6];
    const float* bq = (const float*)d_in[7];
    const float* Wk = (const float*)d_in[8];
    const float* bk = (const float*)d_in[9];
    const float* Wv = (const float*)d_in[10];
    const float* bv = (const float*)d_in[11];
    const float* Wr = (const float*)d_in[12];
    const float* br = (const float*)d_in[13];
    const float* Wo = (const float*)d_in[14];
    const float* bo = (const float*)d_in[15];
    const float* ln_g = (const float*)d_in[16];
    const float* ln_b = (const float*)d_in[17];
    float* out = (float*)d_out;

    char* ws = (char*)d_ws;
    const size_t MB = 1ull << 20;
    short* cat_bf = (short*)(ws + 0 * MB);    // 8 MB
    short* r_bf   = (short*)(ws + 8 * MB);    // 4 MB
    short* Wq_t   = (short*)(ws + 12 * MB);   // dead after proj -> wo out0
    short* Wk_t   = (short*)(ws + 14 * MB);
    short* Wv_t   = (short*)(ws + 16 * MB);   // dead after proj -> wo out1
    short* Wr_t   = (short*)(ws + 18 * MB);
    short* Wo_t   = (short*)(ws + 20 * MB);   // needed until wo_gemm
    short* qw_bf  = (short*)(ws + 22 * MB);
    short* qr_bf  = (short*)(ws + 26 * MB);
    short* k_bf   = (short*)(ws + 30 * MB);   // 8 MB
    short* v_bf   = (short*)(ws + 38 * MB);   // 8 MB
    short* rk_bf  = (short*)(ws + 46 * MB);
    short* vt     = (short*)(ws + 50 * MB);   // 8 MB
    short* av_bf  = (short*)(ws + 58 * MB);
    short* wo0    = Wq_t;                     // 4 MB (12..16)
    short* wo1    = Wv_t;                     // 4 MB (16..20)

    dim3 blk(256);

    // fused casts + weight transposes
    prep_kernel<<<dim3(16, 16, 17), blk, 0, stream>>>(
        mems, w, r, Wq, Wk, Wv, Wr, Wo,
        cat_bf, r_bf, Wq_t, Wk_t, Wv_t, Wr_t, Wo_t);

    // fused projections (K, V, Q->qw/qr scaled, RK)
    proj_gemm_kernel<<<dim3(8, 96), blk, 0, stream>>>(
        cat_bf, r_bf, Wq_t, Wk_t, Wv_t, Wr_t,
        bq, bk, bv, br, rwb, rrb,
        qw_bf, qr_bf, k_bf, v_bf, rk_bf);

    // V transpose
    vtrans_kernel<<<dim3(32, 32), blk, 0, stream>>>(v_bf, vt);

    // attention (windowed bdT combine): grid 512
    attn_mfma_kernel<<<dim3(16, 32), blk, 0, stream>>>(
        qw_bf, qr_bf, k_bf, rk_bf, vt, av_bf);

    // output projection split-K (bf16 partials; summed + bias in LN)
    wo_gemm_kernel<<<dim3(8, 16, 2), blk, 0, stream>>>(av_bf, Wo_t, wo0, wo1);

    // LN(w + wo0 + wo1 + bo)
    ln_kernel<<<dim3(2048), blk, 0, stream>>>(w, wo0, wo1, bo, ln_g, ln_b, out);
}